// Round 15
// baseline (2431.748 us; speedup 1.0000x reference)
//
#include <hip/hip_runtime.h>
#include <math.h>

// Problem constants
#define BB 32
#define TT 512
#define INF_ 128
#define HH 256
#define H3 768
#define NHEADS 4
#define HDIM 64

typedef _Float16 half_t;
typedef half_t half2_t __attribute__((ext_vector_type(2)));
typedef half_t half4_t __attribute__((ext_vector_type(4)));
typedef half_t f16x8 __attribute__((ext_vector_type(8)));
typedef float f32x4 __attribute__((ext_vector_type(4)));

#if defined(__has_builtin)
#if __has_builtin(__builtin_amdgcn_fdot2)
#define FDOT2(a, b, c) __builtin_amdgcn_fdot2((a), (b), (c), false)
#endif
#endif
#ifndef FDOT2
#define FDOT2(a, b, c) fmaf((float)(a).x, (float)(b).x, fmaf((float)(a).y, (float)(b).y, (c)))
#endif

#define BCH(x) __builtin_bit_cast(half2_t, x)
#define PKH(a, b) __builtin_bit_cast(unsigned, half2_t{(half_t)(a), (half_t)(b)})

// ---------------- wave helpers (wave = 64 on CDNA) ----------------
__device__ __forceinline__ float wsum(float v) {
#pragma unroll
  for (int o = 32; o > 0; o >>= 1) v += __shfl_xor(v, o, 64);
  return v;
}
__device__ __forceinline__ float wmax(float v) {
#pragma unroll
  for (int o = 32; o > 0; o >>= 1) v = fmaxf(v, __shfl_xor(v, o, 64));
  return v;
}

// ---------------- fp32 -> f16 cast (n % 1024 == 0) ----------------
__global__ void castk(const float* __restrict__ s, half_t* __restrict__ d, int n) {
  int i = (blockIdx.x * 256 + threadIdx.x) * 4;
  if (i < n) {
    float4 v = *(const float4*)(s + i);
    half4_t o = {(half_t)v.x, (half_t)v.y, (half_t)v.z, (half_t)v.w};
    *(half4_t*)(d + i) = o;
  }
}

// ---------------- MFMA f16 GEMM: C[M,N] = A[M,K] * B[N,K]^T + bias -------
__global__ __launch_bounds__(256) void gemm_f16(
    const half_t* __restrict__ A, const half_t* __restrict__ B,
    const float* __restrict__ bias, float* __restrict__ C,
    int M, int N, int K) {
  __shared__ __align__(16) half_t As[128][40];
  __shared__ __align__(16) half_t Bs[64][40];
  const int tid = threadIdx.x;
  const int wave = tid >> 6, lane = tid & 63;
  const int m0 = blockIdx.y * 128, n0 = blockIdx.x * 64;
  const int mrow = lane & 15, quad = lane >> 4;
  f32x4 acc00 = {0.f, 0.f, 0.f, 0.f}, acc01 = acc00, acc02 = acc00, acc03 = acc00;
  f32x4 acc10 = acc00, acc11 = acc00, acc12 = acc00, acc13 = acc00;
  for (int k0 = 0; k0 < K; k0 += 32) {
    __syncthreads();  // previous iter's fragments consumed
#pragma unroll
    for (int u = 0; u < 2; ++u) {  // stage A: 128 rows x 32 halfs
      int idx = tid + u * 256;
      int row = idx >> 2, seg = idx & 3;
      *(f16x8*)&As[row][seg * 8] =
          *(const f16x8*)&A[(size_t)(m0 + row) * K + k0 + seg * 8];
    }
    {  // stage B: 64 rows x 32 halfs
      int row = tid >> 2, seg = tid & 3;
      *(f16x8*)&Bs[row][seg * 8] =
          *(const f16x8*)&B[(size_t)(n0 + row) * K + k0 + seg * 8];
    }
    __syncthreads();
    f16x8 af0 = *(const f16x8*)&As[wave * 32 + mrow][quad * 8];
    f16x8 af1 = *(const f16x8*)&As[wave * 32 + 16 + mrow][quad * 8];
    f16x8 bf0 = *(const f16x8*)&Bs[mrow][quad * 8];
    f16x8 bf1 = *(const f16x8*)&Bs[16 + mrow][quad * 8];
    f16x8 bf2 = *(const f16x8*)&Bs[32 + mrow][quad * 8];
    f16x8 bf3 = *(const f16x8*)&Bs[48 + mrow][quad * 8];
    acc00 = __builtin_amdgcn_mfma_f32_16x16x32_f16(af0, bf0, acc00, 0, 0, 0);
    acc01 = __builtin_amdgcn_mfma_f32_16x16x32_f16(af0, bf1, acc01, 0, 0, 0);
    acc02 = __builtin_amdgcn_mfma_f32_16x16x32_f16(af0, bf2, acc02, 0, 0, 0);
    acc03 = __builtin_amdgcn_mfma_f32_16x16x32_f16(af0, bf3, acc03, 0, 0, 0);
    acc10 = __builtin_amdgcn_mfma_f32_16x16x32_f16(af1, bf0, acc10, 0, 0, 0);
    acc11 = __builtin_amdgcn_mfma_f32_16x16x32_f16(af1, bf1, acc11, 0, 0, 0);
    acc12 = __builtin_amdgcn_mfma_f32_16x16x32_f16(af1, bf2, acc12, 0, 0, 0);
    acc13 = __builtin_amdgcn_mfma_f32_16x16x32_f16(af1, bf3, acc13, 0, 0, 0);
  }
  float bv0 = bias ? bias[n0 + mrow] : 0.f;
  float bv1 = bias ? bias[n0 + 16 + mrow] : 0.f;
  float bv2 = bias ? bias[n0 + 32 + mrow] : 0.f;
  float bv3 = bias ? bias[n0 + 48 + mrow] : 0.f;
  const int rb = m0 + wave * 32 + quad * 4;
#pragma unroll
  for (int r = 0; r < 4; ++r) {
    float* c0 = C + (size_t)(rb + r) * N + n0;
    c0[mrow] = acc00[r] + bv0;
    c0[16 + mrow] = acc01[r] + bv1;
    c0[32 + mrow] = acc02[r] + bv2;
    c0[48 + mrow] = acc03[r] + bv3;
    float* c1 = C + (size_t)(rb + 16 + r) * N + n0;
    c1[mrow] = acc10[r] + bv0;
    c1[16 + mrow] = acc11[r] + bv1;
    c1[32 + mrow] = acc12[r] + bv2;
    c1[48 + mrow] = acc13[r] + bv3;
  }
}

// ---------------- GRU recurrence: 6-row x 64-col threads ------------------
// R13/R14 model: GRU is LDS-INSTRUCTION-issue bound (8 waves x 35 b128 x
// ~11.7 cyc ~ 3270 cyc/step). h-BYTES are split-invariant but h-INSTRUCTIONS
// are not: thread covering C cols reads C/8 h-b128s. New split: thread
// (j2,kq), tid = kq + 4*j2, owns j = 2j2, 2j2+1 (all 3 gates) x cols
// [64kq,+64) -> h-reads 16->8, streamed stays 19 -> 27 LDS insts/thread
// (-23%). Regs (116 half2): r_j0, r_j1, z_j0 (32 each) + z_j1[0..19].
// Streamed (19 b128 groups @ WSq[g*512+tid], R12-proven conflict-free):
// n_j0 g0-7, n_j1 g8-15, z_j1 tail g16-18. h in hs[2][4][72]: chunk kq at
// 144-B stride -> instruction i hits banks {4i+4kq} = 4 disjoint quads ->
// conflict-free broadcast. Reduce 6 sums via xor1+xor2. One barrier/step.
#define LDW(g, p, a, b, i)                             \
  {                                                    \
    float4 v = (p)[i];                                 \
    g##a = half2_t{(half_t)v.x, (half_t)v.y};          \
    g##b = half2_t{(half_t)v.z, (half_t)v.w};          \
  }
#define LDWALL32(g, p)                                                     \
  LDW(g, p, 0, 1, 0) LDW(g, p, 2, 3, 1) LDW(g, p, 4, 5, 2)                 \
  LDW(g, p, 6, 7, 3) LDW(g, p, 8, 9, 4) LDW(g, p, 10, 11, 5)               \
  LDW(g, p, 12, 13, 6) LDW(g, p, 14, 15, 7) LDW(g, p, 16, 17, 8)           \
  LDW(g, p, 18, 19, 9) LDW(g, p, 20, 21, 10) LDW(g, p, 22, 23, 11)         \
  LDW(g, p, 24, 25, 12) LDW(g, p, 26, 27, 13) LDW(g, p, 28, 29, 14)        \
  LDW(g, p, 30, 31, 15)
#define LDWALL20(g, p)                                                     \
  LDW(g, p, 0, 1, 0) LDW(g, p, 2, 3, 1) LDW(g, p, 4, 5, 2)                 \
  LDW(g, p, 6, 7, 3) LDW(g, p, 8, 9, 4) LDW(g, p, 10, 11, 5)               \
  LDW(g, p, 12, 13, 6) LDW(g, p, 14, 15, 7) LDW(g, p, 16, 17, 8)           \
  LDW(g, p, 18, 19, 9)

#define DECL32(g)                                                          \
  half2_t g##0, g##1, g##2, g##3, g##4, g##5, g##6, g##7, g##8, g##9,      \
      g##10, g##11, g##12, g##13, g##14, g##15, g##16, g##17, g##18,       \
      g##19, g##20, g##21, g##22, g##23, g##24, g##25, g##26, g##27,       \
      g##28, g##29, g##30, g##31;
#define DECL20(g)                                                          \
  half2_t g##0, g##1, g##2, g##3, g##4, g##5, g##6, g##7, g##8, g##9,      \
      g##10, g##11, g##12, g##13, g##14, g##15, g##16, g##17, g##18, g##19;

// i = 0..4: z_j1 from regs (indices a0..a3 <= 19)
#define CHR(i, a0, a1, a2, a3)                                             \
  {                                                                        \
    float4 v = hp4[i];                                                     \
    uint4 n0v = WSq[(i) * 512 + tid];                                      \
    uint4 n1v = WSq[(8 + (i)) * 512 + tid];                                \
    half2_t t0 = __builtin_bit_cast(half2_t, v.x);                         \
    half2_t t1 = __builtin_bit_cast(half2_t, v.y);                         \
    half2_t t2 = __builtin_bit_cast(half2_t, v.z);                         \
    half2_t t3 = __builtin_bit_cast(half2_t, v.w);                         \
    ar0 = FDOT2(wr##a0, t0, ar0); az0 = FDOT2(wz##a0, t0, az0); an0 = FDOT2(BCH(n0v.x), t0, an0); \
    ar1 = FDOT2(wa##a0, t0, ar1); az1 = FDOT2(wb##a0, t0, az1); an1 = FDOT2(BCH(n1v.x), t0, an1); \
    ar0 = FDOT2(wr##a1, t1, ar0); az0 = FDOT2(wz##a1, t1, az0); an0 = FDOT2(BCH(n0v.y), t1, an0); \
    ar1 = FDOT2(wa##a1, t1, ar1); az1 = FDOT2(wb##a1, t1, az1); an1 = FDOT2(BCH(n1v.y), t1, an1); \
    ar0 = FDOT2(wr##a2, t2, ar0); az0 = FDOT2(wz##a2, t2, az0); an0 = FDOT2(BCH(n0v.z), t2, an0); \
    ar1 = FDOT2(wa##a2, t2, ar1); az1 = FDOT2(wb##a2, t2, az1); an1 = FDOT2(BCH(n1v.z), t2, an1); \
    ar0 = FDOT2(wr##a3, t3, ar0); az0 = FDOT2(wz##a3, t3, az0); an0 = FDOT2(BCH(n0v.w), t3, an0); \
    ar1 = FDOT2(wa##a3, t3, ar1); az1 = FDOT2(wb##a3, t3, az1); an1 = FDOT2(BCH(n1v.w), t3, an1); \
  }

// i = 5..7: z_j1 from streamed group zg = 16 + (i-5)
#define CHS(i, a0, a1, a2, a3, zg)                                         \
  {                                                                        \
    float4 v = hp4[i];                                                     \
    uint4 n0v = WSq[(i) * 512 + tid];                                      \
    uint4 n1v = WSq[(8 + (i)) * 512 + tid];                                \
    uint4 z1v = WSq[(zg) * 512 + tid];                                     \
    half2_t t0 = __builtin_bit_cast(half2_t, v.x);                         \
    half2_t t1 = __builtin_bit_cast(half2_t, v.y);                         \
    half2_t t2 = __builtin_bit_cast(half2_t, v.z);                         \
    half2_t t3 = __builtin_bit_cast(half2_t, v.w);                         \
    ar0 = FDOT2(wr##a0, t0, ar0); az0 = FDOT2(wz##a0, t0, az0); an0 = FDOT2(BCH(n0v.x), t0, an0); \
    ar1 = FDOT2(wa##a0, t0, ar1); az1 = FDOT2(BCH(z1v.x), t0, az1); an1 = FDOT2(BCH(n1v.x), t0, an1); \
    ar0 = FDOT2(wr##a1, t1, ar0); az0 = FDOT2(wz##a1, t1, az0); an0 = FDOT2(BCH(n0v.y), t1, an0); \
    ar1 = FDOT2(wa##a1, t1, ar1); az1 = FDOT2(BCH(z1v.y), t1, az1); an1 = FDOT2(BCH(n1v.y), t1, an1); \
    ar0 = FDOT2(wr##a2, t2, ar0); az0 = FDOT2(wz##a2, t2, az0); an0 = FDOT2(BCH(n0v.z), t2, an0); \
    ar1 = FDOT2(wa##a2, t2, ar1); az1 = FDOT2(BCH(z1v.z), t2, az1); an1 = FDOT2(BCH(n1v.z), t2, an1); \
    ar0 = FDOT2(wr##a3, t3, ar0); az0 = FDOT2(wz##a3, t3, az0); an0 = FDOT2(BCH(n0v.w), t3, an0); \
    ar1 = FDOT2(wa##a3, t3, ar1); az1 = FDOT2(BCH(z1v.w), t3, az1); an1 = FDOT2(BCH(n1v.w), t3, an1); \
  }

__device__ __forceinline__ uint4 pk8(const float* p) {
  float4 a = *(const float4*)p;
  float4 b = *(const float4*)(p + 4);
  return uint4{PKH(a.x, a.y), PKH(a.z, a.w), PKH(b.x, b.y), PKH(b.z, b.w)};
}

__global__ __launch_bounds__(512) void gru_layer(
    const float* __restrict__ xp, const float* __restrict__ Whh,
    const float* __restrict__ bhh, float* __restrict__ out,
    half_t* __restrict__ out16) {
  __shared__ __align__(16) uint4 WSq[19 * 512];    // 152 KB streamed weights
  __shared__ __align__(16) half_t hs[2][4][72];
  const int tid = threadIdx.x;
  const int kq = tid & 3, j2 = tid >> 2;
  const int j0 = 2 * j2;
  const int b = blockIdx.x;
  DECL32(wr)   // r row j0
  DECL32(wa)   // r row j0+1
  DECL32(wz)   // z row j0
  DECL20(wb)   // z row j0+1, cols 0..39
  {
    const float4* pr0 = (const float4*)(Whh + (size_t)j0 * HH + kq * 64);
    const float4* pr1 = (const float4*)(Whh + (size_t)(j0 + 1) * HH + kq * 64);
    const float4* pz0 = (const float4*)(Whh + (size_t)(HH + j0) * HH + kq * 64);
    const float4* pz1 = (const float4*)(Whh + (size_t)(HH + j0 + 1) * HH + kq * 64);
    LDWALL32(wr, pr0)
    LDWALL32(wa, pr1)
    LDWALL32(wz, pz0)
    LDWALL20(wb, pz1)
  }
  // Stage streamed weights (19 b128 groups per thread, stride-1 layout)
  {
    const float* rowN0 = Whh + (size_t)(2 * HH + j0) * HH + kq * 64;
    const float* rowN1 = Whh + (size_t)(2 * HH + j0 + 1) * HH + kq * 64;
    const float* rowZ1 = Whh + (size_t)(HH + j0 + 1) * HH + kq * 64;
#pragma unroll
    for (int g = 0; g < 8; ++g) WSq[g * 512 + tid] = pk8(rowN0 + 8 * g);
#pragma unroll
    for (int g = 0; g < 8; ++g) WSq[(8 + g) * 512 + tid] = pk8(rowN1 + 8 * g);
#pragma unroll
    for (int g = 0; g < 3; ++g) WSq[(16 + g) * 512 + tid] = pk8(rowZ1 + 40 + 8 * g);
  }
  const float br0 = bhh[j0], br1 = bhh[j0 + 1];
  const float bz0 = bhh[HH + j0], bz1 = bhh[HH + j0 + 1];
  const float bn0 = bhh[2 * HH + j0], bn1 = bhh[2 * HH + j0 + 1];
  for (int i = tid; i < 288; i += 512) ((unsigned*)hs)[i] = 0u;
  __syncthreads();
  float hprev0 = 0.f, hprev1 = 0.f;
  const float* xrow = xp + (size_t)b * TT * H3;
  float* orow = out + (size_t)b * TT * HH;
  half_t* orow16 = out16 + (size_t)b * TT * HH;
  for (int t = 0; t < TT; ++t) {
    const float4* hp4 = (const float4*)&hs[t & 1][kq][0];
    float ar0 = 0.f, az0 = 0.f, an0 = 0.f, ar1 = 0.f, az1 = 0.f, an1 = 0.f;
    CHR(0, 0, 1, 2, 3)
    CHR(1, 4, 5, 6, 7)
    CHR(2, 8, 9, 10, 11)
    CHR(3, 12, 13, 14, 15)
    CHR(4, 16, 17, 18, 19)
    CHS(5, 20, 21, 22, 23, 16)
    CHS(6, 24, 25, 26, 27, 17)
    CHS(7, 28, 29, 30, 31, 18)
    ar0 += __shfl_xor(ar0, 1); ar0 += __shfl_xor(ar0, 2);
    az0 += __shfl_xor(az0, 1); az0 += __shfl_xor(az0, 2);
    an0 += __shfl_xor(an0, 1); an0 += __shfl_xor(an0, 2);
    ar1 += __shfl_xor(ar1, 1); ar1 += __shfl_xor(ar1, 2);
    az1 += __shfl_xor(az1, 1); az1 += __shfl_xor(az1, 2);
    an1 += __shfl_xor(an1, 1); an1 += __shfl_xor(an1, 2);
    if (kq == 0) {
      float2 xr2 = *(const float2*)(xrow + j0);
      float2 xz2 = *(const float2*)(xrow + HH + j0);
      float2 xn2 = *(const float2*)(xrow + 2 * HH + j0);
      float rg0 = 1.f / (1.f + __expf(-(xr2.x + ar0 + br0)));
      float zg0 = 1.f / (1.f + __expf(-(xz2.x + az0 + bz0)));
      float ng0 = 2.f / (1.f + __expf(-2.f * (xn2.x + rg0 * (an0 + bn0)))) - 1.f;
      float h0 = (1.f - zg0) * ng0 + zg0 * hprev0;
      float rg1 = 1.f / (1.f + __expf(-(xr2.y + ar1 + br1)));
      float zg1 = 1.f / (1.f + __expf(-(xz2.y + az1 + bz1)));
      float ng1 = 2.f / (1.f + __expf(-2.f * (xn2.y + rg1 * (an1 + bn1)))) - 1.f;
      float h1 = (1.f - zg1) * ng1 + zg1 * hprev1;
      hprev0 = h0;
      hprev1 = h1;
      half2_t pk;
      pk.x = (half_t)h0;
      pk.y = (half_t)h1;
      *(half2_t*)&hs[(t + 1) & 1][j2 >> 5][j0 & 63] = pk;
      *(float2*)(orow + j0) = float2{h0, h1};
      *(half2_t*)(orow16 + j0) = pk;
    }
    __syncthreads();
    xrow += H3;
    orow += HH;
    orow16 += HH;
  }
}

// ---------------- gat_W transpose -> f16: [4,256,64] -> [256 cols][256 k] --
__global__ void gat_wt(const float* __restrict__ W, half_t* __restrict__ Wt) {
  int idx = blockIdx.x * 256 + threadIdx.x;  // [0, 65536)
  int col = idx >> 8, k = idx & 255;
  Wt[idx] = (half_t)W[((size_t)((col >> 6) * HH + k)) * HDIM + (col & 63)];
}

// ---------------- GAT f_src/f_dst ----------------
__global__ void gat_fsd(const float* __restrict__ hgat, const float* __restrict__ a,
                        float* __restrict__ fsrc, float* __restrict__ fdst) {
  int b = blockIdx.x, hd = blockIdx.y, t = threadIdx.x;  // block 512
  const float* hp = hgat + ((size_t)(b * TT + t)) * HH + hd * HDIM;
  const float* ap = a + hd * 2 * HDIM;
  float fs = 0.f, fd = 0.f;
#pragma unroll 4
  for (int d = 0; d < HDIM; ++d) {
    float hv = hp[d];
    fs += hv * ap[d];
    fd += hv * ap[HDIM + d];
  }
  fsrc[(b * NHEADS + hd) * TT + t] = fs;
  fdst[(b * NHEADS + hd) * TT + t] = fd;
}

// ---------------- GAT flash attention ----------------
__global__ __launch_bounds__(256) void gat_attn(
    const float* __restrict__ hgat, const float* __restrict__ fsrc,
    const float* __restrict__ fdst, float* __restrict__ out) {
  __shared__ __align__(16) float Ht[128][64];
  __shared__ __align__(16) float fd[128];
  __shared__ __align__(16) float pq[4][128][8];
  const int tid = threadIdx.x, wave = tid >> 6, lane = tid & 63;
  const int hd = blockIdx.y, b = blockIdx.z;
  const int i0 = blockIdx.x * 32 + wave * 8;
  const float* fs = fsrc + (size_t)(b * NHEADS + hd) * TT;
  const float* fdp = fdst + (size_t)(b * NHEADS + hd) * TT;
  float m[8], l[8], acc[8], fi[8];
#pragma unroll
  for (int q = 0; q < 8; ++q) { m[q] = -1e30f; l[q] = 0.f; acc[q] = 0.f; fi[q] = fs[i0 + q]; }
  for (int jt = 0; jt < TT; jt += 128) {
#pragma unroll
    for (int u = 0; u < 8; ++u) {
      int idx = tid + u * 256;
      int jj = idx >> 4, dq = (idx & 15) * 4;
      *(float4*)&Ht[jj][dq] =
          *(const float4*)&hgat[((size_t)(b * TT + jt + jj)) * HH + hd * HDIM + dq];
    }
    if (tid < 128) fd[tid] = fdp[jt + tid];
    __syncthreads();
#pragma unroll
    for (int q = 0; q < 8; ++q) {
      float e0 = fi[q] + fd[lane];      e0 = (e0 > 0.f) ? e0 : 0.2f * e0;
      float e1 = fi[q] + fd[lane + 64]; e1 = (e1 > 0.f) ? e1 : 0.2f * e1;
      float mn = fmaxf(m[q], wmax(fmaxf(e0, e1)));
      float corr = __expf(m[q] - mn);
      float p0 = __expf(e0 - mn), p1 = __expf(e1 - mn);
      l[q] = l[q] * corr + wsum(p0 + p1);
      m[q] = mn;
      acc[q] *= corr;
      pq[wave][lane][q] = p0;
      pq[wave][lane + 64][q] = p1;
    }
#pragma unroll 4
    for (int jj = 0; jj < 128; ++jj) {
      float4 pa = *(const float4*)&pq[wave][jj][0];
      float4 pb = *(const float4*)&pq[wave][jj][4];
      float hv = Ht[jj][lane];
      acc[0] += pa.x * hv; acc[1] += pa.y * hv; acc[2] += pa.z * hv; acc[3] += pa.w * hv;
      acc[4] += pb.x * hv; acc[5] += pb.y * hv; acc[6] += pb.z * hv; acc[7] += pb.w * hv;
    }
    __syncthreads();
  }
#pragma unroll
  for (int q = 0; q < 8; ++q)
    out[((size_t)(b * TT + i0 + q)) * HH + hd * HDIM + lane] = acc[q] / l[q];
}

// ---------------- residual + LayerNorm (f16 output for MFMA GEMM) ---------
__global__ __launch_bounds__(256) void ln_res(
    const float* __restrict__ g, const float* __restrict__ gat,
    const float* __restrict__ gamma, const float* __restrict__ beta,
    half_t* __restrict__ y16) {
  int wave = threadIdx.x >> 6, lane = threadIdx.x & 63;
  size_t n = (size_t)blockIdx.x * 4 + wave;
  float4 v = ((const float4*)(g + n * HH))[lane];
  float4 w = ((const float4*)(gat + n * HH))[lane];
  v.x += w.x; v.y += w.y; v.z += w.z; v.w += w.w;
  float mu = wsum(v.x + v.y + v.z + v.w) * (1.f / 256.f);
  float dx = v.x - mu, dy = v.y - mu, dz = v.z - mu, dw = v.w - mu;
  float var = wsum(dx * dx + dy * dy + dz * dz + dw * dw) * (1.f / 256.f);
  float rstd = rsqrtf(var + 1e-5f);
  float4 gm = ((const float4*)gamma)[lane];
  float4 bt = ((const float4*)beta)[lane];
  half4_t o = {(half_t)(dx * rstd * gm.x + bt.x), (half_t)(dy * rstd * gm.y + bt.y),
               (half_t)(dz * rstd * gm.z + bt.z), (half_t)(dw * rstd * gm.w + bt.w)};
  ((half4_t*)(y16 + n * HH))[lane] = o;
}

// ---------------- MHA flash attention (f16 ctx output) --------------------
__global__ __launch_bounds__(256) void mha_attn(const float* __restrict__ qkv,
                                                half_t* __restrict__ ctx16) {
  __shared__ __align__(16) float KV[8320];        // K^T [64][130] | V [128][64]
  __shared__ __align__(16) float qq[4][64][8];
  __shared__ __align__(16) float pq[4][128][8];
  const int tid = threadIdx.x, wave = tid >> 6, lane = tid & 63;
  const int hd = blockIdx.y, b = blockIdx.z;
  const int i0 = blockIdx.x * 32 + wave * 8;
#pragma unroll
  for (int q = 0; q < 8; ++q)
    qq[wave][lane][q] = qkv[((size_t)(b * TT + i0 + q)) * H3 + hd * HDIM + lane];
  float m[8], l[8], acc[8];
#pragma unroll
  for (int q = 0; q < 8; ++q) { m[q] = -1e30f; l[q] = 0.f; acc[q] = 0.f; }
  for (int jt = 0; jt < TT; jt += 128) {
    // stage K^T: KV[dd*130 + j]
#pragma unroll
    for (int u = 0; u < 8; ++u) {
      int idx = tid + u * 256;
      int jj = idx >> 4, dq = (idx & 15) * 4;
      float4 kv = *(const float4*)&qkv[((size_t)(b * TT + jt + jj)) * H3 + HH + hd * HDIM + dq];
      KV[(dq + 0) * 130 + jj] = kv.x;
      KV[(dq + 1) * 130 + jj] = kv.y;
      KV[(dq + 2) * 130 + jj] = kv.z;
      KV[(dq + 3) * 130 + jj] = kv.w;
    }
    __syncthreads();
    float e0[8] = {}, e1[8] = {};
#pragma unroll 8
    for (int dd = 0; dd < 64; ++dd) {
      float4 qa = *(const float4*)&qq[wave][dd][0];
      float4 qb = *(const float4*)&qq[wave][dd][4];
      float k0 = KV[dd * 130 + lane], k1 = KV[dd * 130 + 64 + lane];
      e0[0] += qa.x * k0; e0[1] += qa.y * k0; e0[2] += qa.z * k0; e0[3] += qa.w * k0;
      e0[4] += qb.x * k0; e0[5] += qb.y * k0; e0[6] += qb.z * k0; e0[7] += qb.w * k0;
      e1[0] += qa.x * k1; e1[1] += qa.y * k1; e1[2] += qa.z * k1; e1[3] += qa.w * k1;
      e1[4] += qb.x * k1; e1[5] += qb.y * k1; e1[6] += qb.z * k1; e1[7] += qb.w * k1;
    }
    __syncthreads();  // done reading K^T
    // stage V over the same buffer: KV[j*64 + dd]
#pragma unroll
    for (int u = 0; u < 8; ++u) {
      int idx = tid + u * 256;
      int jj = idx >> 4, dq = (idx & 15) * 4;
      *(float4*)&KV[jj * 64 + dq] =
          *(const float4*)&qkv[((size_t)(b * TT + jt + jj)) * H3 + 2 * HH + hd * HDIM + dq];
    }
#pragma unroll
    for (int q = 0; q < 8; ++q) {
      float s0 = e0[q] * 0.125f, s1 = e1[q] * 0.125f;
      float mn = fmaxf(m[q], wmax(fmaxf(s0, s1)));
      float corr = __expf(m[q] - mn);
      float p0 = __expf(s0 - mn), p1 = __expf(s1 - mn);
      l[q] = l[q] * corr + wsum(p0 + p1);
      m[q] = mn;
      acc[q] *= corr;
      pq[wave][lane][q] = p0;
      pq[wave][lane + 64][q] = p1;
    }
    __syncthreads();  // V staged, pq written
#pragma unroll 4
    for (int jj = 0; jj < 128; ++jj) {
      float4 pa = *(const float4*)&pq[wave][jj][0];
      float4 pb = *(const float4*)&pq[wave][jj][4];
      float hv = KV[jj * 64 + lane];
      acc[0] += pa.x * hv; acc[1] += pa.y * hv; acc[2] += pa.z * hv; acc[3] += pa.w * hv;
      acc[4] += pb.x * hv; acc[5] += pb.y * hv; acc[6] += pb.z * hv; acc[7] += pb.w * hv;
    }
    __syncthreads();  // before next K^T overwrite
  }
#pragma unroll
  for (int q = 0; q < 8; ++q)
    ctx16[((size_t)(b * TT + i0 + q)) * HH + hd * HDIM + lane] = (half_t)(acc[q] / l[q]);
}

// ---------------- mean pool over T ----------------
__global__ void mean_pool(const float* __restrict__ x, float* __restrict__ out) {
  int b = blockIdx.x, j = threadIdx.x;
  const float* p = x + (size_t)b * TT * HH + j;
  float s = 0.f;
  for (int t = 0; t < TT; ++t) s += p[(size_t)t * HH];
  out[b * HH + j] = s * (1.f / 512.f);
}

// ---------------- FC layers ----------------
__global__ void fc1_k(const float* __restrict__ pooled, const float* __restrict__ w,
                      const float* __restrict__ bias, float* __restrict__ hid) {
  int b = blockIdx.x, o = threadIdx.x;  // 128 threads
  const float* pp = pooled + b * HH;
  const float* wp = w + o * HH;
  float s = 0.f;
#pragma unroll 4
  for (int k = 0; k < HH; ++k) s += pp[k] * wp[k];
  hid[b * 128 + o] = fmaxf(s + bias[o], 0.f);
}

__global__ void fc2_k(const float* __restrict__ hid, const float* __restrict__ w,
                      const float* __restrict__ bias, float* __restrict__ out) {
  int t = threadIdx.x;  // 256 = 32 m x 8 c
  int mm = t >> 3, c = t & 7;
  const float* hp = hid + mm * 128;
  const float* wp = w + c * 128;
  float s = 0.f;
#pragma unroll 4
  for (int k = 0; k < 128; ++k) s += hp[k] * wp[k];
  out[mm * 8 + c] = s + bias[c];
}

extern "C" void kernel_launch(void* const* d_in, const int* in_sizes, int n_in,
                              void* d_out, int out_size, void* d_ws, size_t ws_size,
                              hipStream_t stream) {
  (void)in_sizes; (void)n_in; (void)out_size; (void)ws_size;
  const float* x    = (const float*)d_in[0];
  const float* Wih0 = (const float*)d_in[1];
  const float* Whh0 = (const float*)d_in[2];
  const float* bih0 = (const float*)d_in[3];
  const float* bhh0 = (const float*)d_in[4];
  const float* Wih1 = (const float*)d_in[5];
  const float* Whh1 = (const float*)d_in[6];
  const float* bih1 = (const float*)d_in[7];
  const float* bhh1 = (const float*)d_in[8];
  const float* gatW = (const float*)d_in[9];
  const float* gatA = (const float*)d_in[10];
  const float* lng  = (const float*)d_in[11];
  const float* lnb  = (const float*)d_in[12];
  const float* inw  = (const float*)d_in[13];
  const float* inb  = (const float*)d_in[14];
  const float* outw = (const float*)d_in[15];
  const float* outb = (const float*)d_in[16];
  const float* f1w  = (const float*)d_in[17];
  const float* f1b  = (const float*)d_in[18];
  const float* f2w  = (const float*)d_in[19];
  const float* f2b  = (const float*)d_in[20];
  float* out = (float*)d_out;
  float* ws = (float*)d_ws;

  // fp32 regions:
  float* XPA   = ws;                  // 16384*768: xp0 -> xp1 -> qkv
  float* G0    = ws + 12582912;       // gru0-out -> gat_out
  float* G1    = G0 + 4194304;        // gru1-out (fp32, for ln_res)
  float* Yb    = G1 + 4194304;        // [f16 G0_16 | f16 G1_16] -> attn_out fp32
  float* HGAT  = Yb + 4194304;        // gat feats fp32 -> [f16 CTX16 | f16 Y16]
  float* GATWTf= HGAT + 4194304;
  float* FSRC  = GATWTf + 65536;
  float* FDST  = FSRC + 65536;
  float* POOL  = FDST + 65536;
  float* HIDb  = POOL + 8192;
  float* W16b  = HIDb + 4096;         // f16 weight pool (~1.1 MB)

  // f16 aliases (lifetimes verified against launch order):
  half_t* X16     = (half_t*)G1;                   // dead before gru1 writes G1
  half_t* G0_16   = (half_t*)Yb;                   // dead before attn_out write
  half_t* G1_16   = (half_t*)(Yb + 2097152);
  half_t* CTX16   = (half_t*)HGAT;                 // written after gat phase done
  half_t* Y16     = (half_t*)(HGAT + 2097152);
  half_t* GATWT16 = (half_t*)GATWTf;
  half_t* W16ih0  = (half_t*)W16b;
  half_t* W16ih1  = (half_t*)(W16b + 49152);
  half_t* W16in   = (half_t*)(W16b + 49152 + 98304);
  half_t* W16out  = (half_t*)(W16b + 49152 + 98304 + 98304);

  // 0. casts (weights once; x once)
  castk<<<2048, 256, 0, stream>>>(x, X16, 2097152);
  castk<<<96, 256, 0, stream>>>(Wih0, W16ih0, 98304);
  castk<<<192, 256, 0, stream>>>(Wih1, W16ih1, 196608);
  castk<<<192, 256, 0, stream>>>(inw, W16in, 196608);
  castk<<<64, 256, 0, stream>>>(outw, W16out, 65536);
  gat_wt<<<256, 256, 0, stream>>>(gatW, GATWT16);
  // 1. xp0 = x @ W_ih0^T + b_ih0   (MFMA f16)
  gemm_f16<<<dim3(12, 128), 256, 0, stream>>>(X16, W16ih0, bih0, XPA, 16384, 768, 128);
  // 2. GRU layer 0
  gru_layer<<<32, 512, 0, stream>>>(XPA, Whh0, bhh0, G0, G0_16);
  // 3. xp1 = g0 @ W_ih1^T + b_ih1
  gemm_f16<<<dim3(12, 128), 256, 0, stream>>>(G0_16, W16ih1, bih1, XPA, 16384, 768, 256);
  // 4. GRU layer 1
  gru_layer<<<32, 512, 0, stream>>>(XPA, Whh1, bhh1, G1, G1_16);
  // 5. GAT per-head features + attention
  gemm_f16<<<dim3(4, 128), 256, 0, stream>>>(G1_16, GATWT16, nullptr, HGAT, 16384, 256, 256);
  gat_fsd<<<dim3(32, 4), 512, 0, stream>>>(HGAT, gatA, FSRC, FDST);
  gat_attn<<<dim3(16, 4, 32), 256, 0, stream>>>(HGAT, FSRC, FDST, G0);
  // 6. y = LN(g + gat_out) -> f16
  ln_res<<<4096, 256, 0, stream>>>(G1, G0, lng, lnb, Y16);
  // 7. MHA
  gemm_f16<<<dim3(12, 128), 256, 0, stream>>>(Y16, W16in, inb, XPA, 16384, 768, 256);
  mha_attn<<<dim3(16, 4, 32), 256, 0, stream>>>(XPA, CTX16);
  gemm_f16<<<dim3(4, 128), 256, 0, stream>>>(CTX16, W16out, outb, Yb, 16384, 256, 256);
  // 8. pool + FC head
  mean_pool<<<32, 256, 0, stream>>>(Yb, POOL);
  fc1_k<<<32, 128, 0, stream>>>(POOL, f1w, f1b, HIDb);
  fc2_k<<<1, 256, 0, stream>>>(HIDb, f2w, f2b, out);
}

// Round 16
// 2150.636 us; speedup vs baseline: 1.1307x; 1.1307x over previous
//
#include <hip/hip_runtime.h>
#include <math.h>

// Problem constants
#define BB 32
#define TT 512
#define INF_ 128
#define HH 256
#define H3 768
#define NHEADS 4
#define HDIM 64

typedef _Float16 half_t;
typedef half_t half2_t __attribute__((ext_vector_type(2)));
typedef half_t half4_t __attribute__((ext_vector_type(4)));
typedef half_t f16x8 __attribute__((ext_vector_type(8)));
typedef float f32x4 __attribute__((ext_vector_type(4)));

#if defined(__has_builtin)
#if __has_builtin(__builtin_amdgcn_fdot2)
#define FDOT2(a, b, c) __builtin_amdgcn_fdot2((a), (b), (c), false)
#endif
#endif
#ifndef FDOT2
#define FDOT2(a, b, c) fmaf((float)(a).x, (float)(b).x, fmaf((float)(a).y, (float)(b).y, (c)))
#endif

#define BCH(x) __builtin_bit_cast(half2_t, x)
#define PKH(a, b) __builtin_bit_cast(unsigned, half2_t{(half_t)(a), (half_t)(b)})

// ---------------- wave helpers (wave = 64 on CDNA) ----------------
__device__ __forceinline__ float wsum(float v) {
#pragma unroll
  for (int o = 32; o > 0; o >>= 1) v += __shfl_xor(v, o, 64);
  return v;
}
__device__ __forceinline__ float wmax(float v) {
#pragma unroll
  for (int o = 32; o > 0; o >>= 1) v = fmaxf(v, __shfl_xor(v, o, 64));
  return v;
}

// ---------------- fp32 -> f16 cast (n % 1024 == 0) ----------------
__global__ void castk(const float* __restrict__ s, half_t* __restrict__ d, int n) {
  int i = (blockIdx.x * 256 + threadIdx.x) * 4;
  if (i < n) {
    float4 v = *(const float4*)(s + i);
    half4_t o = {(half_t)v.x, (half_t)v.y, (half_t)v.z, (half_t)v.w};
    *(half4_t*)(d + i) = o;
  }
}

// ---------------- MFMA f16 GEMM: C[M,N] = A[M,K] * B[N,K]^T + bias -------
__global__ __launch_bounds__(256) void gemm_f16(
    const half_t* __restrict__ A, const half_t* __restrict__ B,
    const float* __restrict__ bias, float* __restrict__ C,
    int M, int N, int K) {
  __shared__ __align__(16) half_t As[128][40];
  __shared__ __align__(16) half_t Bs[64][40];
  const int tid = threadIdx.x;
  const int wave = tid >> 6, lane = tid & 63;
  const int m0 = blockIdx.y * 128, n0 = blockIdx.x * 64;
  const int mrow = lane & 15, quad = lane >> 4;
  f32x4 acc00 = {0.f, 0.f, 0.f, 0.f}, acc01 = acc00, acc02 = acc00, acc03 = acc00;
  f32x4 acc10 = acc00, acc11 = acc00, acc12 = acc00, acc13 = acc00;
  for (int k0 = 0; k0 < K; k0 += 32) {
    __syncthreads();  // previous iter's fragments consumed
#pragma unroll
    for (int u = 0; u < 2; ++u) {  // stage A: 128 rows x 32 halfs
      int idx = tid + u * 256;
      int row = idx >> 2, seg = idx & 3;
      *(f16x8*)&As[row][seg * 8] =
          *(const f16x8*)&A[(size_t)(m0 + row) * K + k0 + seg * 8];
    }
    {  // stage B: 64 rows x 32 halfs
      int row = tid >> 2, seg = tid & 3;
      *(f16x8*)&Bs[row][seg * 8] =
          *(const f16x8*)&B[(size_t)(n0 + row) * K + k0 + seg * 8];
    }
    __syncthreads();
    f16x8 af0 = *(const f16x8*)&As[wave * 32 + mrow][quad * 8];
    f16x8 af1 = *(const f16x8*)&As[wave * 32 + 16 + mrow][quad * 8];
    f16x8 bf0 = *(const f16x8*)&Bs[mrow][quad * 8];
    f16x8 bf1 = *(const f16x8*)&Bs[16 + mrow][quad * 8];
    f16x8 bf2 = *(const f16x8*)&Bs[32 + mrow][quad * 8];
    f16x8 bf3 = *(const f16x8*)&Bs[48 + mrow][quad * 8];
    acc00 = __builtin_amdgcn_mfma_f32_16x16x32_f16(af0, bf0, acc00, 0, 0, 0);
    acc01 = __builtin_amdgcn_mfma_f32_16x16x32_f16(af0, bf1, acc01, 0, 0, 0);
    acc02 = __builtin_amdgcn_mfma_f32_16x16x32_f16(af0, bf2, acc02, 0, 0, 0);
    acc03 = __builtin_amdgcn_mfma_f32_16x16x32_f16(af0, bf3, acc03, 0, 0, 0);
    acc10 = __builtin_amdgcn_mfma_f32_16x16x32_f16(af1, bf0, acc10, 0, 0, 0);
    acc11 = __builtin_amdgcn_mfma_f32_16x16x32_f16(af1, bf1, acc11, 0, 0, 0);
    acc12 = __builtin_amdgcn_mfma_f32_16x16x32_f16(af1, bf2, acc12, 0, 0, 0);
    acc13 = __builtin_amdgcn_mfma_f32_16x16x32_f16(af1, bf3, acc13, 0, 0, 0);
  }
  float bv0 = bias ? bias[n0 + mrow] : 0.f;
  float bv1 = bias ? bias[n0 + 16 + mrow] : 0.f;
  float bv2 = bias ? bias[n0 + 32 + mrow] : 0.f;
  float bv3 = bias ? bias[n0 + 48 + mrow] : 0.f;
  const int rb = m0 + wave * 32 + quad * 4;
#pragma unroll
  for (int r = 0; r < 4; ++r) {
    float* c0 = C + (size_t)(rb + r) * N + n0;
    c0[mrow] = acc00[r] + bv0;
    c0[16 + mrow] = acc01[r] + bv1;
    c0[32 + mrow] = acc02[r] + bv2;
    c0[48 + mrow] = acc03[r] + bv3;
    float* c1 = C + (size_t)(rb + 16 + r) * N + n0;
    c1[mrow] = acc10[r] + bv0;
    c1[16 + mrow] = acc11[r] + bv1;
    c1[32 + mrow] = acc12[r] + bv2;
    c1[48 + mrow] = acc13[r] + bv3;
  }
}

// ---------------- GRU recurrence: 6-row x 64-col threads ------------------
// R15 lesson: the 6x64 split (27 vs 35 LDS insts/thread) is sound, but
// moving the xp loads after the reduction exposed ~900 cyc of HBM
// first-touch latency per step (+1130 cyc measured). Fix: issue the
// (kq==0)-masked xp loads at the TOP of the loop body -> ~2500 cyc of
// dot-chain slack hides them, as in R14. Thread (j2,kq), tid = kq+4*j2,
// owns j = 2j2,2j2+1 (all 3 gates) x cols [64kq,+64). Regs: r_j0, r_j1,
// z_j0 (32 half2 each) + z_j1[0..19] = 116. Streamed (19 b128 groups at
// WSq[g*512+tid], R12-proven conflict-free): n_j0 g0-7, n_j1 g8-15,
// z_j1 tail g16-18. h in hs[2][4][72]: chunk kq at 144-B stride -> 4
// disjoint bank quads -> conflict-free broadcasts (R15: 0 conflicts).
// Reduce 6 sums via xor1+xor2. One barrier per step.
#define LDW(g, p, a, b, i)                             \
  {                                                    \
    float4 v = (p)[i];                                 \
    g##a = half2_t{(half_t)v.x, (half_t)v.y};          \
    g##b = half2_t{(half_t)v.z, (half_t)v.w};          \
  }
#define LDWALL32(g, p)                                                     \
  LDW(g, p, 0, 1, 0) LDW(g, p, 2, 3, 1) LDW(g, p, 4, 5, 2)                 \
  LDW(g, p, 6, 7, 3) LDW(g, p, 8, 9, 4) LDW(g, p, 10, 11, 5)               \
  LDW(g, p, 12, 13, 6) LDW(g, p, 14, 15, 7) LDW(g, p, 16, 17, 8)           \
  LDW(g, p, 18, 19, 9) LDW(g, p, 20, 21, 10) LDW(g, p, 22, 23, 11)         \
  LDW(g, p, 24, 25, 12) LDW(g, p, 26, 27, 13) LDW(g, p, 28, 29, 14)        \
  LDW(g, p, 30, 31, 15)
#define LDWALL20(g, p)                                                     \
  LDW(g, p, 0, 1, 0) LDW(g, p, 2, 3, 1) LDW(g, p, 4, 5, 2)                 \
  LDW(g, p, 6, 7, 3) LDW(g, p, 8, 9, 4) LDW(g, p, 10, 11, 5)               \
  LDW(g, p, 12, 13, 6) LDW(g, p, 14, 15, 7) LDW(g, p, 16, 17, 8)           \
  LDW(g, p, 18, 19, 9)

#define DECL32(g)                                                          \
  half2_t g##0, g##1, g##2, g##3, g##4, g##5, g##6, g##7, g##8, g##9,      \
      g##10, g##11, g##12, g##13, g##14, g##15, g##16, g##17, g##18,       \
      g##19, g##20, g##21, g##22, g##23, g##24, g##25, g##26, g##27,       \
      g##28, g##29, g##30, g##31;
#define DECL20(g)                                                          \
  half2_t g##0, g##1, g##2, g##3, g##4, g##5, g##6, g##7, g##8, g##9,      \
      g##10, g##11, g##12, g##13, g##14, g##15, g##16, g##17, g##18, g##19;

// i = 0..4: z_j1 from regs (indices a0..a3 <= 19)
#define CHR(i, a0, a1, a2, a3)                                             \
  {                                                                        \
    float4 v = hp4[i];                                                     \
    uint4 n0v = WSq[(i) * 512 + tid];                                      \
    uint4 n1v = WSq[(8 + (i)) * 512 + tid];                                \
    half2_t t0 = __builtin_bit_cast(half2_t, v.x);                         \
    half2_t t1 = __builtin_bit_cast(half2_t, v.y);                         \
    half2_t t2 = __builtin_bit_cast(half2_t, v.z);                         \
    half2_t t3 = __builtin_bit_cast(half2_t, v.w);                         \
    ar0 = FDOT2(wr##a0, t0, ar0); az0 = FDOT2(wz##a0, t0, az0); an0 = FDOT2(BCH(n0v.x), t0, an0); \
    ar1 = FDOT2(wa##a0, t0, ar1); az1 = FDOT2(wb##a0, t0, az1); an1 = FDOT2(BCH(n1v.x), t0, an1); \
    ar0 = FDOT2(wr##a1, t1, ar0); az0 = FDOT2(wz##a1, t1, az0); an0 = FDOT2(BCH(n0v.y), t1, an0); \
    ar1 = FDOT2(wa##a1, t1, ar1); az1 = FDOT2(wb##a1, t1, az1); an1 = FDOT2(BCH(n1v.y), t1, an1); \
    ar0 = FDOT2(wr##a2, t2, ar0); az0 = FDOT2(wz##a2, t2, az0); an0 = FDOT2(BCH(n0v.z), t2, an0); \
    ar1 = FDOT2(wa##a2, t2, ar1); az1 = FDOT2(wb##a2, t2, az1); an1 = FDOT2(BCH(n1v.z), t2, an1); \
    ar0 = FDOT2(wr##a3, t3, ar0); az0 = FDOT2(wz##a3, t3, az0); an0 = FDOT2(BCH(n0v.w), t3, an0); \
    ar1 = FDOT2(wa##a3, t3, ar1); az1 = FDOT2(wb##a3, t3, az1); an1 = FDOT2(BCH(n1v.w), t3, an1); \
  }

// i = 5..7: z_j1 from streamed group zg = 16 + (i-5)
#define CHS(i, a0, a1, a2, a3, zg)                                         \
  {                                                                        \
    float4 v = hp4[i];                                                     \
    uint4 n0v = WSq[(i) * 512 + tid];                                      \
    uint4 n1v = WSq[(8 + (i)) * 512 + tid];                                \
    uint4 z1v = WSq[(zg) * 512 + tid];                                     \
    half2_t t0 = __builtin_bit_cast(half2_t, v.x);                         \
    half2_t t1 = __builtin_bit_cast(half2_t, v.y);                         \
    half2_t t2 = __builtin_bit_cast(half2_t, v.z);                         \
    half2_t t3 = __builtin_bit_cast(half2_t, v.w);                         \
    ar0 = FDOT2(wr##a0, t0, ar0); az0 = FDOT2(wz##a0, t0, az0); an0 = FDOT2(BCH(n0v.x), t0, an0); \
    ar1 = FDOT2(wa##a0, t0, ar1); az1 = FDOT2(BCH(z1v.x), t0, az1); an1 = FDOT2(BCH(n1v.x), t0, an1); \
    ar0 = FDOT2(wr##a1, t1, ar0); az0 = FDOT2(wz##a1, t1, az0); an0 = FDOT2(BCH(n0v.y), t1, an0); \
    ar1 = FDOT2(wa##a1, t1, ar1); az1 = FDOT2(BCH(z1v.y), t1, az1); an1 = FDOT2(BCH(n1v.y), t1, an1); \
    ar0 = FDOT2(wr##a2, t2, ar0); az0 = FDOT2(wz##a2, t2, az0); an0 = FDOT2(BCH(n0v.z), t2, an0); \
    ar1 = FDOT2(wa##a2, t2, ar1); az1 = FDOT2(BCH(z1v.z), t2, az1); an1 = FDOT2(BCH(n1v.z), t2, an1); \
    ar0 = FDOT2(wr##a3, t3, ar0); az0 = FDOT2(wz##a3, t3, az0); an0 = FDOT2(BCH(n0v.w), t3, an0); \
    ar1 = FDOT2(wa##a3, t3, ar1); az1 = FDOT2(BCH(z1v.w), t3, az1); an1 = FDOT2(BCH(n1v.w), t3, an1); \
  }

__device__ __forceinline__ uint4 pk8(const float* p) {
  float4 a = *(const float4*)p;
  float4 b = *(const float4*)(p + 4);
  return uint4{PKH(a.x, a.y), PKH(a.z, a.w), PKH(b.x, b.y), PKH(b.z, b.w)};
}

__global__ __launch_bounds__(512) void gru_layer(
    const float* __restrict__ xp, const float* __restrict__ Whh,
    const float* __restrict__ bhh, float* __restrict__ out,
    half_t* __restrict__ out16) {
  __shared__ __align__(16) uint4 WSq[19 * 512];    // 152 KB streamed weights
  __shared__ __align__(16) half_t hs[2][4][72];
  const int tid = threadIdx.x;
  const int kq = tid & 3, j2 = tid >> 2;
  const int j0 = 2 * j2;
  const int b = blockIdx.x;
  DECL32(wr)   // r row j0
  DECL32(wa)   // r row j0+1
  DECL32(wz)   // z row j0
  DECL20(wb)   // z row j0+1, cols 0..39
  {
    const float4* pr0 = (const float4*)(Whh + (size_t)j0 * HH + kq * 64);
    const float4* pr1 = (const float4*)(Whh + (size_t)(j0 + 1) * HH + kq * 64);
    const float4* pz0 = (const float4*)(Whh + (size_t)(HH + j0) * HH + kq * 64);
    const float4* pz1 = (const float4*)(Whh + (size_t)(HH + j0 + 1) * HH + kq * 64);
    LDWALL32(wr, pr0)
    LDWALL32(wa, pr1)
    LDWALL32(wz, pz0)
    LDWALL20(wb, pz1)
  }
  // Stage streamed weights (19 b128 groups per thread, stride-1 layout)
  {
    const float* rowN0 = Whh + (size_t)(2 * HH + j0) * HH + kq * 64;
    const float* rowN1 = Whh + (size_t)(2 * HH + j0 + 1) * HH + kq * 64;
    const float* rowZ1 = Whh + (size_t)(HH + j0 + 1) * HH + kq * 64;
#pragma unroll
    for (int g = 0; g < 8; ++g) WSq[g * 512 + tid] = pk8(rowN0 + 8 * g);
#pragma unroll
    for (int g = 0; g < 8; ++g) WSq[(8 + g) * 512 + tid] = pk8(rowN1 + 8 * g);
#pragma unroll
    for (int g = 0; g < 3; ++g) WSq[(16 + g) * 512 + tid] = pk8(rowZ1 + 40 + 8 * g);
  }
  const float br0 = bhh[j0], br1 = bhh[j0 + 1];
  const float bz0 = bhh[HH + j0], bz1 = bhh[HH + j0 + 1];
  const float bn0 = bhh[2 * HH + j0], bn1 = bhh[2 * HH + j0 + 1];
  for (int i = tid; i < 288; i += 512) ((unsigned*)hs)[i] = 0u;
  __syncthreads();
  float hprev0 = 0.f, hprev1 = 0.f;
  const float* xrow = xp + (size_t)b * TT * H3;
  float* orow = out + (size_t)b * TT * HH;
  half_t* orow16 = out16 + (size_t)b * TT * HH;
  for (int t = 0; t < TT; ++t) {
    // Issue xp loads FIRST (kq==0 lanes only): ~2500 cyc of dot-chain slack
    // hides the HBM first-touch latency (R15's regression: loads after the
    // reduction exposed ~900 cyc/step).
    float2 xr2 = {0.f, 0.f}, xz2 = {0.f, 0.f}, xn2 = {0.f, 0.f};
    if (kq == 0) {
      xr2 = *(const float2*)(xrow + j0);
      xz2 = *(const float2*)(xrow + HH + j0);
      xn2 = *(const float2*)(xrow + 2 * HH + j0);
    }
    const float4* hp4 = (const float4*)&hs[t & 1][kq][0];
    float ar0 = 0.f, az0 = 0.f, an0 = 0.f, ar1 = 0.f, az1 = 0.f, an1 = 0.f;
    CHR(0, 0, 1, 2, 3)
    CHR(1, 4, 5, 6, 7)
    CHR(2, 8, 9, 10, 11)
    CHR(3, 12, 13, 14, 15)
    CHR(4, 16, 17, 18, 19)
    CHS(5, 20, 21, 22, 23, 16)
    CHS(6, 24, 25, 26, 27, 17)
    CHS(7, 28, 29, 30, 31, 18)
    ar0 += __shfl_xor(ar0, 1); ar0 += __shfl_xor(ar0, 2);
    az0 += __shfl_xor(az0, 1); az0 += __shfl_xor(az0, 2);
    an0 += __shfl_xor(an0, 1); an0 += __shfl_xor(an0, 2);
    ar1 += __shfl_xor(ar1, 1); ar1 += __shfl_xor(ar1, 2);
    az1 += __shfl_xor(az1, 1); az1 += __shfl_xor(az1, 2);
    an1 += __shfl_xor(an1, 1); an1 += __shfl_xor(an1, 2);
    if (kq == 0) {
      float rg0 = 1.f / (1.f + __expf(-(xr2.x + ar0 + br0)));
      float zg0 = 1.f / (1.f + __expf(-(xz2.x + az0 + bz0)));
      float ng0 = 2.f / (1.f + __expf(-2.f * (xn2.x + rg0 * (an0 + bn0)))) - 1.f;
      float h0 = (1.f - zg0) * ng0 + zg0 * hprev0;
      float rg1 = 1.f / (1.f + __expf(-(xr2.y + ar1 + br1)));
      float zg1 = 1.f / (1.f + __expf(-(xz2.y + az1 + bz1)));
      float ng1 = 2.f / (1.f + __expf(-2.f * (xn2.y + rg1 * (an1 + bn1)))) - 1.f;
      float h1 = (1.f - zg1) * ng1 + zg1 * hprev1;
      hprev0 = h0;
      hprev1 = h1;
      half2_t pk;
      pk.x = (half_t)h0;
      pk.y = (half_t)h1;
      *(half2_t*)&hs[(t + 1) & 1][j2 >> 5][j0 & 63] = pk;
      *(float2*)(orow + j0) = float2{h0, h1};
      *(half2_t*)(orow16 + j0) = pk;
    }
    __syncthreads();
    xrow += H3;
    orow += HH;
    orow16 += HH;
  }
}

// ---------------- gat_W transpose -> f16: [4,256,64] -> [256 cols][256 k] --
__global__ void gat_wt(const float* __restrict__ W, half_t* __restrict__ Wt) {
  int idx = blockIdx.x * 256 + threadIdx.x;  // [0, 65536)
  int col = idx >> 8, k = idx & 255;
  Wt[idx] = (half_t)W[((size_t)((col >> 6) * HH + k)) * HDIM + (col & 63)];
}

// ---------------- GAT f_src/f_dst ----------------
__global__ void gat_fsd(const float* __restrict__ hgat, const float* __restrict__ a,
                        float* __restrict__ fsrc, float* __restrict__ fdst) {
  int b = blockIdx.x, hd = blockIdx.y, t = threadIdx.x;  // block 512
  const float* hp = hgat + ((size_t)(b * TT + t)) * HH + hd * HDIM;
  const float* ap = a + hd * 2 * HDIM;
  float fs = 0.f, fd = 0.f;
#pragma unroll 4
  for (int d = 0; d < HDIM; ++d) {
    float hv = hp[d];
    fs += hv * ap[d];
    fd += hv * ap[HDIM + d];
  }
  fsrc[(b * NHEADS + hd) * TT + t] = fs;
  fdst[(b * NHEADS + hd) * TT + t] = fd;
}

// ---------------- GAT flash attention ----------------
__global__ __launch_bounds__(256) void gat_attn(
    const float* __restrict__ hgat, const float* __restrict__ fsrc,
    const float* __restrict__ fdst, float* __restrict__ out) {
  __shared__ __align__(16) float Ht[128][64];
  __shared__ __align__(16) float fd[128];
  __shared__ __align__(16) float pq[4][128][8];
  const int tid = threadIdx.x, wave = tid >> 6, lane = tid & 63;
  const int hd = blockIdx.y, b = blockIdx.z;
  const int i0 = blockIdx.x * 32 + wave * 8;
  const float* fs = fsrc + (size_t)(b * NHEADS + hd) * TT;
  const float* fdp = fdst + (size_t)(b * NHEADS + hd) * TT;
  float m[8], l[8], acc[8], fi[8];
#pragma unroll
  for (int q = 0; q < 8; ++q) { m[q] = -1e30f; l[q] = 0.f; acc[q] = 0.f; fi[q] = fs[i0 + q]; }
  for (int jt = 0; jt < TT; jt += 128) {
#pragma unroll
    for (int u = 0; u < 8; ++u) {
      int idx = tid + u * 256;
      int jj = idx >> 4, dq = (idx & 15) * 4;
      *(float4*)&Ht[jj][dq] =
          *(const float4*)&hgat[((size_t)(b * TT + jt + jj)) * HH + hd * HDIM + dq];
    }
    if (tid < 128) fd[tid] = fdp[jt + tid];
    __syncthreads();
#pragma unroll
    for (int q = 0; q < 8; ++q) {
      float e0 = fi[q] + fd[lane];      e0 = (e0 > 0.f) ? e0 : 0.2f * e0;
      float e1 = fi[q] + fd[lane + 64]; e1 = (e1 > 0.f) ? e1 : 0.2f * e1;
      float mn = fmaxf(m[q], wmax(fmaxf(e0, e1)));
      float corr = __expf(m[q] - mn);
      float p0 = __expf(e0 - mn), p1 = __expf(e1 - mn);
      l[q] = l[q] * corr + wsum(p0 + p1);
      m[q] = mn;
      acc[q] *= corr;
      pq[wave][lane][q] = p0;
      pq[wave][lane + 64][q] = p1;
    }
#pragma unroll 4
    for (int jj = 0; jj < 128; ++jj) {
      float4 pa = *(const float4*)&pq[wave][jj][0];
      float4 pb = *(const float4*)&pq[wave][jj][4];
      float hv = Ht[jj][lane];
      acc[0] += pa.x * hv; acc[1] += pa.y * hv; acc[2] += pa.z * hv; acc[3] += pa.w * hv;
      acc[4] += pb.x * hv; acc[5] += pb.y * hv; acc[6] += pb.z * hv; acc[7] += pb.w * hv;
    }
    __syncthreads();
  }
#pragma unroll
  for (int q = 0; q < 8; ++q)
    out[((size_t)(b * TT + i0 + q)) * HH + hd * HDIM + lane] = acc[q] / l[q];
}

// ---------------- residual + LayerNorm (f16 output for MFMA GEMM) ---------
__global__ __launch_bounds__(256) void ln_res(
    const float* __restrict__ g, const float* __restrict__ gat,
    const float* __restrict__ gamma, const float* __restrict__ beta,
    half_t* __restrict__ y16) {
  int wave = threadIdx.x >> 6, lane = threadIdx.x & 63;
  size_t n = (size_t)blockIdx.x * 4 + wave;
  float4 v = ((const float4*)(g + n * HH))[lane];
  float4 w = ((const float4*)(gat + n * HH))[lane];
  v.x += w.x; v.y += w.y; v.z += w.z; v.w += w.w;
  float mu = wsum(v.x + v.y + v.z + v.w) * (1.f / 256.f);
  float dx = v.x - mu, dy = v.y - mu, dz = v.z - mu, dw = v.w - mu;
  float var = wsum(dx * dx + dy * dy + dz * dz + dw * dw) * (1.f / 256.f);
  float rstd = rsqrtf(var + 1e-5f);
  float4 gm = ((const float4*)gamma)[lane];
  float4 bt = ((const float4*)beta)[lane];
  half4_t o = {(half_t)(dx * rstd * gm.x + bt.x), (half_t)(dy * rstd * gm.y + bt.y),
               (half_t)(dz * rstd * gm.z + bt.z), (half_t)(dw * rstd * gm.w + bt.w)};
  ((half4_t*)(y16 + n * HH))[lane] = o;
}

// ---------------- MHA flash attention (f16 ctx output) --------------------
__global__ __launch_bounds__(256) void mha_attn(const float* __restrict__ qkv,
                                                half_t* __restrict__ ctx16) {
  __shared__ __align__(16) float KV[8320];        // K^T [64][130] | V [128][64]
  __shared__ __align__(16) float qq[4][64][8];
  __shared__ __align__(16) float pq[4][128][8];
  const int tid = threadIdx.x, wave = tid >> 6, lane = tid & 63;
  const int hd = blockIdx.y, b = blockIdx.z;
  const int i0 = blockIdx.x * 32 + wave * 8;
#pragma unroll
  for (int q = 0; q < 8; ++q)
    qq[wave][lane][q] = qkv[((size_t)(b * TT + i0 + q)) * H3 + hd * HDIM + lane];
  float m[8], l[8], acc[8];
#pragma unroll
  for (int q = 0; q < 8; ++q) { m[q] = -1e30f; l[q] = 0.f; acc[q] = 0.f; }
  for (int jt = 0; jt < TT; jt += 128) {
    // stage K^T: KV[dd*130 + j]
#pragma unroll
    for (int u = 0; u < 8; ++u) {
      int idx = tid + u * 256;
      int jj = idx >> 4, dq = (idx & 15) * 4;
      float4 kv = *(const float4*)&qkv[((size_t)(b * TT + jt + jj)) * H3 + HH + hd * HDIM + dq];
      KV[(dq + 0) * 130 + jj] = kv.x;
      KV[(dq + 1) * 130 + jj] = kv.y;
      KV[(dq + 2) * 130 + jj] = kv.z;
      KV[(dq + 3) * 130 + jj] = kv.w;
    }
    __syncthreads();
    float e0[8] = {}, e1[8] = {};
#pragma unroll 8
    for (int dd = 0; dd < 64; ++dd) {
      float4 qa = *(const float4*)&qq[wave][dd][0];
      float4 qb = *(const float4*)&qq[wave][dd][4];
      float k0 = KV[dd * 130 + lane], k1 = KV[dd * 130 + 64 + lane];
      e0[0] += qa.x * k0; e0[1] += qa.y * k0; e0[2] += qa.z * k0; e0[3] += qa.w * k0;
      e0[4] += qb.x * k0; e0[5] += qb.y * k0; e0[6] += qb.z * k0; e0[7] += qb.w * k0;
      e1[0] += qa.x * k1; e1[1] += qa.y * k1; e1[2] += qa.z * k1; e1[3] += qa.w * k1;
      e1[4] += qb.x * k1; e1[5] += qb.y * k1; e1[6] += qb.z * k1; e1[7] += qb.w * k1;
    }
    __syncthreads();  // done reading K^T
    // stage V over the same buffer: KV[j*64 + dd]
#pragma unroll
    for (int u = 0; u < 8; ++u) {
      int idx = tid + u * 256;
      int jj = idx >> 4, dq = (idx & 15) * 4;
      *(float4*)&KV[jj * 64 + dq] =
          *(const float4*)&qkv[((size_t)(b * TT + jt + jj)) * H3 + 2 * HH + hd * HDIM + dq];
    }
#pragma unroll
    for (int q = 0; q < 8; ++q) {
      float s0 = e0[q] * 0.125f, s1 = e1[q] * 0.125f;
      float mn = fmaxf(m[q], wmax(fmaxf(s0, s1)));
      float corr = __expf(m[q] - mn);
      float p0 = __expf(s0 - mn), p1 = __expf(s1 - mn);
      l[q] = l[q] * corr + wsum(p0 + p1);
      m[q] = mn;
      acc[q] *= corr;
      pq[wave][lane][q] = p0;
      pq[wave][lane + 64][q] = p1;
    }
    __syncthreads();  // V staged, pq written
#pragma unroll 4
    for (int jj = 0; jj < 128; ++jj) {
      float4 pa = *(const float4*)&pq[wave][jj][0];
      float4 pb = *(const float4*)&pq[wave][jj][4];
      float hv = KV[jj * 64 + lane];
      acc[0] += pa.x * hv; acc[1] += pa.y * hv; acc[2] += pa.z * hv; acc[3] += pa.w * hv;
      acc[4] += pb.x * hv; acc[5] += pb.y * hv; acc[6] += pb.z * hv; acc[7] += pb.w * hv;
    }
    __syncthreads();  // before next K^T overwrite
  }
#pragma unroll
  for (int q = 0; q < 8; ++q)
    ctx16[((size_t)(b * TT + i0 + q)) * HH + hd * HDIM + lane] = (half_t)(acc[q] / l[q]);
}

// ---------------- mean pool over T ----------------
__global__ void mean_pool(const float* __restrict__ x, float* __restrict__ out) {
  int b = blockIdx.x, j = threadIdx.x;
  const float* p = x + (size_t)b * TT * HH + j;
  float s = 0.f;
  for (int t = 0; t < TT; ++t) s += p[(size_t)t * HH];
  out[b * HH + j] = s * (1.f / 512.f);
}

// ---------------- FC layers ----------------
__global__ void fc1_k(const float* __restrict__ pooled, const float* __restrict__ w,
                      const float* __restrict__ bias, float* __restrict__ hid) {
  int b = blockIdx.x, o = threadIdx.x;  // 128 threads
  const float* pp = pooled + b * HH;
  const float* wp = w + o * HH;
  float s = 0.f;
#pragma unroll 4
  for (int k = 0; k < HH; ++k) s += pp[k] * wp[k];
  hid[b * 128 + o] = fmaxf(s + bias[o], 0.f);
}

__global__ void fc2_k(const float* __restrict__ hid, const float* __restrict__ w,
                      const float* __restrict__ bias, float* __restrict__ out) {
  int t = threadIdx.x;  // 256 = 32 m x 8 c
  int mm = t >> 3, c = t & 7;
  const float* hp = hid + mm * 128;
  const float* wp = w + c * 128;
  float s = 0.f;
#pragma unroll 4
  for (int k = 0; k < 128; ++k) s += hp[k] * wp[k];
  out[mm * 8 + c] = s + bias[c];
}

extern "C" void kernel_launch(void* const* d_in, const int* in_sizes, int n_in,
                              void* d_out, int out_size, void* d_ws, size_t ws_size,
                              hipStream_t stream) {
  (void)in_sizes; (void)n_in; (void)out_size; (void)ws_size;
  const float* x    = (const float*)d_in[0];
  const float* Wih0 = (const float*)d_in[1];
  const float* Whh0 = (const float*)d_in[2];
  const float* bih0 = (const float*)d_in[3];
  const float* bhh0 = (const float*)d_in[4];
  const float* Wih1 = (const float*)d_in[5];
  const float* Whh1 = (const float*)d_in[6];
  const float* bih1 = (const float*)d_in[7];
  const float* bhh1 = (const float*)d_in[8];
  const float* gatW = (const float*)d_in[9];
  const float* gatA = (const float*)d_in[10];
  const float* lng  = (const float*)d_in[11];
  const float* lnb  = (const float*)d_in[12];
  const float* inw  = (const float*)d_in[13];
  const float* inb  = (const float*)d_in[14];
  const float* outw = (const float*)d_in[15];
  const float* outb = (const float*)d_in[16];
  const float* f1w  = (const float*)d_in[17];
  const float* f1b  = (const float*)d_in[18];
  const float* f2w  = (const float*)d_in[19];
  const float* f2b  = (const float*)d_in[20];
  float* out = (float*)d_out;
  float* ws = (float*)d_ws;

  // fp32 regions:
  float* XPA   = ws;                  // 16384*768: xp0 -> xp1 -> qkv
  float* G0    = ws + 12582912;       // gru0-out -> gat_out
  float* G1    = G0 + 4194304;        // gru1-out (fp32, for ln_res)
  float* Yb    = G1 + 4194304;        // [f16 G0_16 | f16 G1_16] -> attn_out fp32
  float* HGAT  = Yb + 4194304;        // gat feats fp32 -> [f16 CTX16 | f16 Y16]
  float* GATWTf= HGAT + 4194304;
  float* FSRC  = GATWTf + 65536;
  float* FDST  = FSRC + 65536;
  float* POOL  = FDST + 65536;
  float* HIDb  = POOL + 8192;
  float* W16b  = HIDb + 4096;         // f16 weight pool (~1.1 MB)

  // f16 aliases (lifetimes verified against launch order):
  half_t* X16     = (half_t*)G1;                   // dead before gru1 writes G1
  half_t* G0_16   = (half_t*)Yb;                   // dead before attn_out write
  half_t* G1_16   = (half_t*)(Yb + 2097152);
  half_t* CTX16   = (half_t*)HGAT;                 // written after gat phase done
  half_t* Y16     = (half_t*)(HGAT + 2097152);
  half_t* GATWT16 = (half_t*)GATWTf;
  half_t* W16ih0  = (half_t*)W16b;
  half_t* W16ih1  = (half_t*)(W16b + 49152);
  half_t* W16in   = (half_t*)(W16b + 49152 + 98304);
  half_t* W16out  = (half_t*)(W16b + 49152 + 98304 + 98304);

  // 0. casts (weights once; x once)
  castk<<<2048, 256, 0, stream>>>(x, X16, 2097152);
  castk<<<96, 256, 0, stream>>>(Wih0, W16ih0, 98304);
  castk<<<192, 256, 0, stream>>>(Wih1, W16ih1, 196608);
  castk<<<192, 256, 0, stream>>>(inw, W16in, 196608);
  castk<<<64, 256, 0, stream>>>(outw, W16out, 65536);
  gat_wt<<<256, 256, 0, stream>>>(gatW, GATWT16);
  // 1. xp0 = x @ W_ih0^T + b_ih0   (MFMA f16)
  gemm_f16<<<dim3(12, 128), 256, 0, stream>>>(X16, W16ih0, bih0, XPA, 16384, 768, 128);
  // 2. GRU layer 0
  gru_layer<<<32, 512, 0, stream>>>(XPA, Whh0, bhh0, G0, G0_16);
  // 3. xp1 = g0 @ W_ih1^T + b_ih1
  gemm_f16<<<dim3(12, 128), 256, 0, stream>>>(G0_16, W16ih1, bih1, XPA, 16384, 768, 256);
  // 4. GRU layer 1
  gru_layer<<<32, 512, 0, stream>>>(XPA, Whh1, bhh1, G1, G1_16);
  // 5. GAT per-head features + attention
  gemm_f16<<<dim3(4, 128), 256, 0, stream>>>(G1_16, GATWT16, nullptr, HGAT, 16384, 256, 256);
  gat_fsd<<<dim3(32, 4), 512, 0, stream>>>(HGAT, gatA, FSRC, FDST);
  gat_attn<<<dim3(16, 4, 32), 256, 0, stream>>>(HGAT, FSRC, FDST, G0);
  // 6. y = LN(g + gat_out) -> f16
  ln_res<<<4096, 256, 0, stream>>>(G1, G0, lng, lnb, Y16);
  // 7. MHA
  gemm_f16<<<dim3(12, 128), 256, 0, stream>>>(Y16, W16in, inb, XPA, 16384, 768, 256);
  mha_attn<<<dim3(16, 4, 32), 256, 0, stream>>>(XPA, CTX16);
  gemm_f16<<<dim3(4, 128), 256, 0, stream>>>(CTX16, W16out, outb, Yb, 16384, 256, 256);
  // 8. pool + FC head
  mean_pool<<<32, 256, 0, stream>>>(Yb, POOL);
  fc1_k<<<32, 128, 0, stream>>>(POOL, f1w, f1b, HIDb);
  fc2_k<<<1, 256, 0, stream>>>(HIDb, f2w, f2b, out);
}

// Round 17
// 1907.977 us; speedup vs baseline: 1.2745x; 1.1272x over previous
//
#include <hip/hip_runtime.h>
#include <math.h>

// Problem constants
#define BB 32
#define TT 512
#define INF_ 128
#define HH 256
#define H3 768
#define NHEADS 4
#define HDIM 64

typedef _Float16 half_t;
typedef half_t half2_t __attribute__((ext_vector_type(2)));
typedef half_t half4_t __attribute__((ext_vector_type(4)));
typedef half_t f16x8 __attribute__((ext_vector_type(8)));
typedef float f32x4 __attribute__((ext_vector_type(4)));

#if defined(__has_builtin)
#if __has_builtin(__builtin_amdgcn_fdot2)
#define FDOT2(a, b, c) __builtin_amdgcn_fdot2((a), (b), (c), false)
#endif
#endif
#ifndef FDOT2
#define FDOT2(a, b, c) fmaf((float)(a).x, (float)(b).x, fmaf((float)(a).y, (float)(b).y, (c)))
#endif

#define BCH(x) __builtin_bit_cast(half2_t, x)
#define PKH(a, b) __builtin_bit_cast(unsigned, half2_t{(half_t)(a), (half_t)(b)})

// ---------------- wave helpers (wave = 64 on CDNA) ----------------
__device__ __forceinline__ float wsum(float v) {
#pragma unroll
  for (int o = 32; o > 0; o >>= 1) v += __shfl_xor(v, o, 64);
  return v;
}
__device__ __forceinline__ float wmax(float v) {
#pragma unroll
  for (int o = 32; o > 0; o >>= 1) v = fmaxf(v, __shfl_xor(v, o, 64));
  return v;
}

// ---------------- fp32 -> f16 cast (n % 1024 == 0) ----------------
__global__ void castk(const float* __restrict__ s, half_t* __restrict__ d, int n) {
  int i = (blockIdx.x * 256 + threadIdx.x) * 4;
  if (i < n) {
    float4 v = *(const float4*)(s + i);
    half4_t o = {(half_t)v.x, (half_t)v.y, (half_t)v.z, (half_t)v.w};
    *(half4_t*)(d + i) = o;
  }
}

// ---------------- MFMA f16 GEMM: C[M,N] = A[M,K] * B[N,K]^T + bias -------
__global__ __launch_bounds__(256) void gemm_f16(
    const half_t* __restrict__ A, const half_t* __restrict__ B,
    const float* __restrict__ bias, float* __restrict__ C,
    int M, int N, int K) {
  __shared__ __align__(16) half_t As[128][40];
  __shared__ __align__(16) half_t Bs[64][40];
  const int tid = threadIdx.x;
  const int wave = tid >> 6, lane = tid & 63;
  const int m0 = blockIdx.y * 128, n0 = blockIdx.x * 64;
  const int mrow = lane & 15, quad = lane >> 4;
  f32x4 acc00 = {0.f, 0.f, 0.f, 0.f}, acc01 = acc00, acc02 = acc00, acc03 = acc00;
  f32x4 acc10 = acc00, acc11 = acc00, acc12 = acc00, acc13 = acc00;
  for (int k0 = 0; k0 < K; k0 += 32) {
    __syncthreads();  // previous iter's fragments consumed
#pragma unroll
    for (int u = 0; u < 2; ++u) {  // stage A: 128 rows x 32 halfs
      int idx = tid + u * 256;
      int row = idx >> 2, seg = idx & 3;
      *(f16x8*)&As[row][seg * 8] =
          *(const f16x8*)&A[(size_t)(m0 + row) * K + k0 + seg * 8];
    }
    {  // stage B: 64 rows x 32 halfs
      int row = tid >> 2, seg = tid & 3;
      *(f16x8*)&Bs[row][seg * 8] =
          *(const f16x8*)&B[(size_t)(n0 + row) * K + k0 + seg * 8];
    }
    __syncthreads();
    f16x8 af0 = *(const f16x8*)&As[wave * 32 + mrow][quad * 8];
    f16x8 af1 = *(const f16x8*)&As[wave * 32 + 16 + mrow][quad * 8];
    f16x8 bf0 = *(const f16x8*)&Bs[mrow][quad * 8];
    f16x8 bf1 = *(const f16x8*)&Bs[16 + mrow][quad * 8];
    f16x8 bf2 = *(const f16x8*)&Bs[32 + mrow][quad * 8];
    f16x8 bf3 = *(const f16x8*)&Bs[48 + mrow][quad * 8];
    acc00 = __builtin_amdgcn_mfma_f32_16x16x32_f16(af0, bf0, acc00, 0, 0, 0);
    acc01 = __builtin_amdgcn_mfma_f32_16x16x32_f16(af0, bf1, acc01, 0, 0, 0);
    acc02 = __builtin_amdgcn_mfma_f32_16x16x32_f16(af0, bf2, acc02, 0, 0, 0);
    acc03 = __builtin_amdgcn_mfma_f32_16x16x32_f16(af0, bf3, acc03, 0, 0, 0);
    acc10 = __builtin_amdgcn_mfma_f32_16x16x32_f16(af1, bf0, acc10, 0, 0, 0);
    acc11 = __builtin_amdgcn_mfma_f32_16x16x32_f16(af1, bf1, acc11, 0, 0, 0);
    acc12 = __builtin_amdgcn_mfma_f32_16x16x32_f16(af1, bf2, acc12, 0, 0, 0);
    acc13 = __builtin_amdgcn_mfma_f32_16x16x32_f16(af1, bf3, acc13, 0, 0, 0);
  }
  float bv0 = bias ? bias[n0 + mrow] : 0.f;
  float bv1 = bias ? bias[n0 + 16 + mrow] : 0.f;
  float bv2 = bias ? bias[n0 + 32 + mrow] : 0.f;
  float bv3 = bias ? bias[n0 + 48 + mrow] : 0.f;
  const int rb = m0 + wave * 32 + quad * 4;
#pragma unroll
  for (int r = 0; r < 4; ++r) {
    float* c0 = C + (size_t)(rb + r) * N + n0;
    c0[mrow] = acc00[r] + bv0;
    c0[16 + mrow] = acc01[r] + bv1;
    c0[32 + mrow] = acc02[r] + bv2;
    c0[48 + mrow] = acc03[r] + bv3;
    float* c1 = C + (size_t)(rb + 16 + r) * N + n0;
    c1[mrow] = acc10[r] + bv0;
    c1[16 + mrow] = acc11[r] + bv1;
    c1[32 + mrow] = acc12[r] + bv2;
    c1[48 + mrow] = acc13[r] + bv3;
  }
}

// ---------------- GRU recurrence: R14-exact 3x128 structure ---------------
// R14 (3 gate-rows x 128 cols, 35 LDS insts/thread) measured 699 us; the
// R15/R16 6x64 split (27 insts) measured 809-941 despite fewer LDS insts -
// empirically falsified, reverted. Only change vs R14: fp32 out is
// NULLABLE (uniform branch) - layer 0's fp32 h is never read (only the f16
// copy feeds the next GEMM), dropping a 32 MB write stream.
// Thread (j,kh): regs r,z chunks 0-13 + n chunk 0 = 116 half2; streamed 19
// b128 groups at WSq[g*512+tid] (stride-1, 0 conflicts); h packed-f16 in
// hs[2][2][144] (+32B pad, broadcast reads). One barrier/step.
#define LDW(g, p, a, b, i)                             \
  {                                                    \
    float4 v = (p)[i];                                 \
    g##a = half2_t{(half_t)v.x, (half_t)v.y};          \
    g##b = half2_t{(half_t)v.z, (half_t)v.w};          \
  }
#define LDW28(g, p)                                                        \
  LDW(g, p, 0, 1, 0) LDW(g, p, 2, 3, 1) LDW(g, p, 4, 5, 2)                 \
  LDW(g, p, 6, 7, 3) LDW(g, p, 8, 9, 4) LDW(g, p, 10, 11, 5)               \
  LDW(g, p, 12, 13, 6) LDW(g, p, 14, 15, 7) LDW(g, p, 16, 17, 8)           \
  LDW(g, p, 18, 19, 9) LDW(g, p, 20, 21, 10) LDW(g, p, 22, 23, 11)         \
  LDW(g, p, 24, 25, 12) LDW(g, p, 26, 27, 13) LDW(g, p, 28, 29, 14)        \
  LDW(g, p, 30, 31, 15) LDW(g, p, 32, 33, 16) LDW(g, p, 34, 35, 17)        \
  LDW(g, p, 36, 37, 18) LDW(g, p, 38, 39, 19) LDW(g, p, 40, 41, 20)        \
  LDW(g, p, 42, 43, 21) LDW(g, p, 44, 45, 22) LDW(g, p, 46, 47, 23)        \
  LDW(g, p, 48, 49, 24) LDW(g, p, 50, 51, 25) LDW(g, p, 52, 53, 26)        \
  LDW(g, p, 54, 55, 27)

#define DECL56(g)                                                          \
  half2_t g##0, g##1, g##2, g##3, g##4, g##5, g##6, g##7, g##8, g##9,      \
      g##10, g##11, g##12, g##13, g##14, g##15, g##16, g##17, g##18,       \
      g##19, g##20, g##21, g##22, g##23, g##24, g##25, g##26, g##27,       \
      g##28, g##29, g##30, g##31, g##32, g##33, g##34, g##35, g##36,       \
      g##37, g##38, g##39, g##40, g##41, g##42, g##43, g##44, g##45,       \
      g##46, g##47, g##48, g##49, g##50, g##51, g##52, g##53, g##54, g##55;

// chunks 1..13: r,z from regs, n from one b128 group (group c8-1)
#define CHA(c8, a0, a1, a2, a3)                                            \
  {                                                                        \
    float4 v = hp4[c8];                                                    \
    uint4 nv = WSq[((c8)-1) * 512 + tid];                                  \
    half2_t t0 = __builtin_bit_cast(half2_t, v.x);                         \
    half2_t t1 = __builtin_bit_cast(half2_t, v.y);                         \
    half2_t t2 = __builtin_bit_cast(half2_t, v.z);                         \
    half2_t t3 = __builtin_bit_cast(half2_t, v.w);                         \
    ar = FDOT2(wr##a0, t0, ar); az = FDOT2(wz##a0, t0, az); an = FDOT2(BCH(nv.x), t0, an); \
    ar = FDOT2(wr##a1, t1, ar); az = FDOT2(wz##a1, t1, az); an = FDOT2(BCH(nv.y), t1, an); \
    ar = FDOT2(wr##a2, t2, ar); az = FDOT2(wz##a2, t2, az); an = FDOT2(BCH(nv.z), t2, an); \
    ar = FDOT2(wr##a3, t3, ar); az = FDOT2(wz##a3, t3, az); an = FDOT2(BCH(nv.w), t3, an); \
  }

// chunks 14,15: r,z,n all from LDS b128 groups
#define CHB(c8)                                                            \
  {                                                                        \
    float4 v = hp4[c8];                                                    \
    uint4 nv = WSq[((c8)-1) * 512 + tid];                                  \
    uint4 rv = WSq[(15 + ((c8)-14)) * 512 + tid];                          \
    uint4 zv = WSq[(17 + ((c8)-14)) * 512 + tid];                          \
    half2_t t0 = __builtin_bit_cast(half2_t, v.x);                         \
    half2_t t1 = __builtin_bit_cast(half2_t, v.y);                         \
    half2_t t2 = __builtin_bit_cast(half2_t, v.z);                         \
    half2_t t3 = __builtin_bit_cast(half2_t, v.w);                         \
    ar = FDOT2(BCH(rv.x), t0, ar); az = FDOT2(BCH(zv.x), t0, az); an = FDOT2(BCH(nv.x), t0, an); \
    ar = FDOT2(BCH(rv.y), t1, ar); az = FDOT2(BCH(zv.y), t1, az); an = FDOT2(BCH(nv.y), t1, an); \
    ar = FDOT2(BCH(rv.z), t2, ar); az = FDOT2(BCH(zv.z), t2, az); an = FDOT2(BCH(nv.z), t2, an); \
    ar = FDOT2(BCH(rv.w), t3, ar); az = FDOT2(BCH(zv.w), t3, az); an = FDOT2(BCH(nv.w), t3, an); \
  }

__device__ __forceinline__ uint4 pk8(const float* p) {
  float4 a = *(const float4*)p;
  float4 b = *(const float4*)(p + 4);
  return uint4{PKH(a.x, a.y), PKH(a.z, a.w), PKH(b.x, b.y), PKH(b.z, b.w)};
}

__global__ __launch_bounds__(512) void gru_layer(
    const float* __restrict__ xp, const float* __restrict__ Whh,
    const float* __restrict__ bhh, float* __restrict__ out,
    half_t* __restrict__ out16) {
  __shared__ __align__(16) uint4 WSq[19 * 512];    // 152 KB streamed weights
  __shared__ __align__(16) half_t hs[2][2][144];
  const int tid = threadIdx.x;
  const int kh = tid & 1, j = tid >> 1;
  const int b = blockIdx.x;
  const bool wf32 = (out != nullptr);  // uniform: layer 0 skips fp32 h-store
  DECL56(wr)
  DECL56(wz)
  half2_t wn0, wn1, wn2, wn3;
  {
    const float4* pr = (const float4*)(Whh + (size_t)j * HH + kh * 128);
    const float4* pz = (const float4*)(Whh + (size_t)(HH + j) * HH + kh * 128);
    const float4* pn = (const float4*)(Whh + (size_t)(2 * HH + j) * HH + kh * 128);
    LDW28(wr, pr)
    LDW28(wz, pz)
    LDW(wn, pn, 0, 1, 0)
    LDW(wn, pn, 2, 3, 1)
  }
  // Stage streamed weights: 19 b128 groups of 4 slots each per thread.
  {
    const float* rowN = Whh + (size_t)(2 * HH + j) * HH + kh * 128;
    const float* rowR = Whh + (size_t)j * HH + kh * 128;
    const float* rowZ = Whh + (size_t)(HH + j) * HH + kh * 128;
#pragma unroll
    for (int sg = 0; sg < 15; ++sg) WSq[sg * 512 + tid] = pk8(rowN + 8 + 8 * sg);
#pragma unroll
    for (int sg = 0; sg < 2; ++sg) WSq[(15 + sg) * 512 + tid] = pk8(rowR + 112 + 8 * sg);
#pragma unroll
    for (int sg = 0; sg < 2; ++sg) WSq[(17 + sg) * 512 + tid] = pk8(rowZ + 112 + 8 * sg);
  }
  const float br = bhh[j], bz = bhh[HH + j], bn = bhh[2 * HH + j];
  for (int i = tid; i < 288; i += 512) ((unsigned*)hs)[i] = 0u;
  __syncthreads();
  float hprev = 0.f;
  const float* xrow = xp + (size_t)b * TT * H3;
  float* orow = out + (size_t)b * TT * HH;
  half_t* orow16 = out16 + (size_t)b * TT * HH;
  for (int t = 0; t < TT; ++t) {
    float xr = xrow[j], xz = xrow[HH + j], xn = xrow[2 * HH + j];
    const float4* hp4 = (const float4*)&hs[t & 1][kh][0];
    float ar = 0.f, az = 0.f, an = 0.f;
    {  // chunk 0: r,z,n all regs
      float4 v = hp4[0];
      half2_t t0 = __builtin_bit_cast(half2_t, v.x);
      half2_t t1 = __builtin_bit_cast(half2_t, v.y);
      half2_t t2 = __builtin_bit_cast(half2_t, v.z);
      half2_t t3 = __builtin_bit_cast(half2_t, v.w);
      ar = FDOT2(wr0, t0, ar); az = FDOT2(wz0, t0, az); an = FDOT2(wn0, t0, an);
      ar = FDOT2(wr1, t1, ar); az = FDOT2(wz1, t1, az); an = FDOT2(wn1, t1, an);
      ar = FDOT2(wr2, t2, ar); az = FDOT2(wz2, t2, az); an = FDOT2(wn2, t2, an);
      ar = FDOT2(wr3, t3, ar); az = FDOT2(wz3, t3, az); an = FDOT2(wn3, t3, an);
    }
    CHA(1, 4, 5, 6, 7)
    CHA(2, 8, 9, 10, 11)
    CHA(3, 12, 13, 14, 15)
    CHA(4, 16, 17, 18, 19)
    CHA(5, 20, 21, 22, 23)
    CHA(6, 24, 25, 26, 27)
    CHA(7, 28, 29, 30, 31)
    CHA(8, 32, 33, 34, 35)
    CHA(9, 36, 37, 38, 39)
    CHA(10, 40, 41, 42, 43)
    CHA(11, 44, 45, 46, 47)
    CHA(12, 48, 49, 50, 51)
    CHA(13, 52, 53, 54, 55)
    CHB(14)
    CHB(15)
    ar += __shfl_xor(ar, 1);
    az += __shfl_xor(az, 1);
    an += __shfl_xor(an, 1);
    float rg = 1.f / (1.f + __expf(-(xr + ar + br)));
    float zg = 1.f / (1.f + __expf(-(xz + az + bz)));
    float ng = 2.f / (1.f + __expf(-2.f * (xn + rg * (an + bn)))) - 1.f;  // tanh, inf-safe
    float hnew = (1.f - zg) * ng + zg * hprev;
    hprev = hnew;
    float hpart = __shfl_xor(hnew, 2);  // lane (kh=0, even j) gets h_{j+1}
    if ((tid & 3) == 0) {               // kh==0 && j even: one b32 packed write
      half2_t pk;
      pk.x = (half_t)hnew;
      pk.y = (half_t)hpart;
      *(half2_t*)&hs[(t + 1) & 1][j >> 7][j & 127] = pk;
    }
    if (kh == 0) {
      orow16[j] = (half_t)hnew;
      if (wf32) orow[j] = hnew;
    }
    __syncthreads();
    xrow += H3;
    orow += HH;
    orow16 += HH;
  }
}

// ---------------- gat_W transpose -> f16: [4,256,64] -> [256 cols][256 k] --
__global__ void gat_wt(const float* __restrict__ W, half_t* __restrict__ Wt) {
  int idx = blockIdx.x * 256 + threadIdx.x;  // [0, 65536)
  int col = idx >> 8, k = idx & 255;
  Wt[idx] = (half_t)W[((size_t)((col >> 6) * HH + k)) * HDIM + (col & 63)];
}

// ---------------- GAT f_src/f_dst ----------------
__global__ void gat_fsd(const float* __restrict__ hgat, const float* __restrict__ a,
                        float* __restrict__ fsrc, float* __restrict__ fdst) {
  int b = blockIdx.x, hd = blockIdx.y, t = threadIdx.x;  // block 512
  const float* hp = hgat + ((size_t)(b * TT + t)) * HH + hd * HDIM;
  const float* ap = a + hd * 2 * HDIM;
  float fs = 0.f, fd = 0.f;
#pragma unroll 4
  for (int d = 0; d < HDIM; ++d) {
    float hv = hp[d];
    fs += hv * ap[d];
    fd += hv * ap[HDIM + d];
  }
  fsrc[(b * NHEADS + hd) * TT + t] = fs;
  fdst[(b * NHEADS + hd) * TT + t] = fd;
}

// ---------------- GAT flash attention ----------------
__global__ __launch_bounds__(256) void gat_attn(
    const float* __restrict__ hgat, const float* __restrict__ fsrc,
    const float* __restrict__ fdst, float* __restrict__ out) {
  __shared__ __align__(16) float Ht[128][64];
  __shared__ __align__(16) float fd[128];
  __shared__ __align__(16) float pq[4][128][8];
  const int tid = threadIdx.x, wave = tid >> 6, lane = tid & 63;
  const int hd = blockIdx.y, b = blockIdx.z;
  const int i0 = blockIdx.x * 32 + wave * 8;
  const float* fs = fsrc + (size_t)(b * NHEADS + hd) * TT;
  const float* fdp = fdst + (size_t)(b * NHEADS + hd) * TT;
  float m[8], l[8], acc[8], fi[8];
#pragma unroll
  for (int q = 0; q < 8; ++q) { m[q] = -1e30f; l[q] = 0.f; acc[q] = 0.f; fi[q] = fs[i0 + q]; }
  for (int jt = 0; jt < TT; jt += 128) {
#pragma unroll
    for (int u = 0; u < 8; ++u) {
      int idx = tid + u * 256;
      int jj = idx >> 4, dq = (idx & 15) * 4;
      *(float4*)&Ht[jj][dq] =
          *(const float4*)&hgat[((size_t)(b * TT + jt + jj)) * HH + hd * HDIM + dq];
    }
    if (tid < 128) fd[tid] = fdp[jt + tid];
    __syncthreads();
#pragma unroll
    for (int q = 0; q < 8; ++q) {
      float e0 = fi[q] + fd[lane];      e0 = (e0 > 0.f) ? e0 : 0.2f * e0;
      float e1 = fi[q] + fd[lane + 64]; e1 = (e1 > 0.f) ? e1 : 0.2f * e1;
      float mn = fmaxf(m[q], wmax(fmaxf(e0, e1)));
      float corr = __expf(m[q] - mn);
      float p0 = __expf(e0 - mn), p1 = __expf(e1 - mn);
      l[q] = l[q] * corr + wsum(p0 + p1);
      m[q] = mn;
      acc[q] *= corr;
      pq[wave][lane][q] = p0;
      pq[wave][lane + 64][q] = p1;
    }
#pragma unroll 4
    for (int jj = 0; jj < 128; ++jj) {
      float4 pa = *(const float4*)&pq[wave][jj][0];
      float4 pb = *(const float4*)&pq[wave][jj][4];
      float hv = Ht[jj][lane];
      acc[0] += pa.x * hv; acc[1] += pa.y * hv; acc[2] += pa.z * hv; acc[3] += pa.w * hv;
      acc[4] += pb.x * hv; acc[5] += pb.y * hv; acc[6] += pb.z * hv; acc[7] += pb.w * hv;
    }
    __syncthreads();
  }
#pragma unroll
  for (int q = 0; q < 8; ++q)
    out[((size_t)(b * TT + i0 + q)) * HH + hd * HDIM + lane] = acc[q] / l[q];
}

// ---------------- residual + LayerNorm (f16 output for MFMA GEMM) ---------
__global__ __launch_bounds__(256) void ln_res(
    const float* __restrict__ g, const float* __restrict__ gat,
    const float* __restrict__ gamma, const float* __restrict__ beta,
    half_t* __restrict__ y16) {
  int wave = threadIdx.x >> 6, lane = threadIdx.x & 63;
  size_t n = (size_t)blockIdx.x * 4 + wave;
  float4 v = ((const float4*)(g + n * HH))[lane];
  float4 w = ((const float4*)(gat + n * HH))[lane];
  v.x += w.x; v.y += w.y; v.z += w.z; v.w += w.w;
  float mu = wsum(v.x + v.y + v.z + v.w) * (1.f / 256.f);
  float dx = v.x - mu, dy = v.y - mu, dz = v.z - mu, dw = v.w - mu;
  float var = wsum(dx * dx + dy * dy + dz * dz + dw * dw) * (1.f / 256.f);
  float rstd = rsqrtf(var + 1e-5f);
  float4 gm = ((const float4*)gamma)[lane];
  float4 bt = ((const float4*)beta)[lane];
  half4_t o = {(half_t)(dx * rstd * gm.x + bt.x), (half_t)(dy * rstd * gm.y + bt.y),
               (half_t)(dz * rstd * gm.z + bt.z), (half_t)(dw * rstd * gm.w + bt.w)};
  ((half4_t*)(y16 + n * HH))[lane] = o;
}

// ---------------- MHA flash attention (f16 ctx output) --------------------
__global__ __launch_bounds__(256) void mha_attn(const float* __restrict__ qkv,
                                                half_t* __restrict__ ctx16) {
  __shared__ __align__(16) float KV[8320];        // K^T [64][130] | V [128][64]
  __shared__ __align__(16) float qq[4][64][8];
  __shared__ __align__(16) float pq[4][128][8];
  const int tid = threadIdx.x, wave = tid >> 6, lane = tid & 63;
  const int hd = blockIdx.y, b = blockIdx.z;
  const int i0 = blockIdx.x * 32 + wave * 8;
#pragma unroll
  for (int q = 0; q < 8; ++q)
    qq[wave][lane][q] = qkv[((size_t)(b * TT + i0 + q)) * H3 + hd * HDIM + lane];
  float m[8], l[8], acc[8];
#pragma unroll
  for (int q = 0; q < 8; ++q) { m[q] = -1e30f; l[q] = 0.f; acc[q] = 0.f; }
  for (int jt = 0; jt < TT; jt += 128) {
    // stage K^T: KV[dd*130 + j]
#pragma unroll
    for (int u = 0; u < 8; ++u) {
      int idx = tid + u * 256;
      int jj = idx >> 4, dq = (idx & 15) * 4;
      float4 kv = *(const float4*)&qkv[((size_t)(b * TT + jt + jj)) * H3 + HH + hd * HDIM + dq];
      KV[(dq + 0) * 130 + jj] = kv.x;
      KV[(dq + 1) * 130 + jj] = kv.y;
      KV[(dq + 2) * 130 + jj] = kv.z;
      KV[(dq + 3) * 130 + jj] = kv.w;
    }
    __syncthreads();
    float e0[8] = {}, e1[8] = {};
#pragma unroll 8
    for (int dd = 0; dd < 64; ++dd) {
      float4 qa = *(const float4*)&qq[wave][dd][0];
      float4 qb = *(const float4*)&qq[wave][dd][4];
      float k0 = KV[dd * 130 + lane], k1 = KV[dd * 130 + 64 + lane];
      e0[0] += qa.x * k0; e0[1] += qa.y * k0; e0[2] += qa.z * k0; e0[3] += qa.w * k0;
      e0[4] += qb.x * k0; e0[5] += qb.y * k0; e0[6] += qb.z * k0; e0[7] += qb.w * k0;
      e1[0] += qa.x * k1; e1[1] += qa.y * k1; e1[2] += qa.z * k1; e1[3] += qa.w * k1;
      e1[4] += qb.x * k1; e1[5] += qb.y * k1; e1[6] += qb.z * k1; e1[7] += qb.w * k1;
    }
    __syncthreads();  // done reading K^T
    // stage V over the same buffer: KV[j*64 + dd]
#pragma unroll
    for (int u = 0; u < 8; ++u) {
      int idx = tid + u * 256;
      int jj = idx >> 4, dq = (idx & 15) * 4;
      *(float4*)&KV[jj * 64 + dq] =
          *(const float4*)&qkv[((size_t)(b * TT + jt + jj)) * H3 + 2 * HH + hd * HDIM + dq];
    }
#pragma unroll
    for (int q = 0; q < 8; ++q) {
      float s0 = e0[q] * 0.125f, s1 = e1[q] * 0.125f;
      float mn = fmaxf(m[q], wmax(fmaxf(s0, s1)));
      float corr = __expf(m[q] - mn);
      float p0 = __expf(s0 - mn), p1 = __expf(s1 - mn);
      l[q] = l[q] * corr + wsum(p0 + p1);
      m[q] = mn;
      acc[q] *= corr;
      pq[wave][lane][q] = p0;
      pq[wave][lane + 64][q] = p1;
    }
    __syncthreads();  // V staged, pq written
#pragma unroll 4
    for (int jj = 0; jj < 128; ++jj) {
      float4 pa = *(const float4*)&pq[wave][jj][0];
      float4 pb = *(const float4*)&pq[wave][jj][4];
      float hv = KV[jj * 64 + lane];
      acc[0] += pa.x * hv; acc[1] += pa.y * hv; acc[2] += pa.z * hv; acc[3] += pa.w * hv;
      acc[4] += pb.x * hv; acc[5] += pb.y * hv; acc[6] += pb.z * hv; acc[7] += pb.w * hv;
    }
    __syncthreads();  // before next K^T overwrite
  }
#pragma unroll
  for (int q = 0; q < 8; ++q)
    ctx16[((size_t)(b * TT + i0 + q)) * HH + hd * HDIM + lane] = (half_t)(acc[q] / l[q]);
}

// ---------------- mean pool over T ----------------
__global__ void mean_pool(const float* __restrict__ x, float* __restrict__ out) {
  int b = blockIdx.x, j = threadIdx.x;
  const float* p = x + (size_t)b * TT * HH + j;
  float s = 0.f;
  for (int t = 0; t < TT; ++t) s += p[(size_t)t * HH];
  out[b * HH + j] = s * (1.f / 512.f);
}

// ---------------- FC layers ----------------
__global__ void fc1_k(const float* __restrict__ pooled, const float* __restrict__ w,
                      const float* __restrict__ bias, float* __restrict__ hid) {
  int b = blockIdx.x, o = threadIdx.x;  // 128 threads
  const float* pp = pooled + b * HH;
  const float* wp = w + o * HH;
  float s = 0.f;
#pragma unroll 4
  for (int k = 0; k < HH; ++k) s += pp[k] * wp[k];
  hid[b * 128 + o] = fmaxf(s + bias[o], 0.f);
}

__global__ void fc2_k(const float* __restrict__ hid, const float* __restrict__ w,
                      const float* __restrict__ bias, float* __restrict__ out) {
  int t = threadIdx.x;  // 256 = 32 m x 8 c
  int mm = t >> 3, c = t & 7;
  const float* hp = hid + mm * 128;
  const float* wp = w + c * 128;
  float s = 0.f;
#pragma unroll 4
  for (int k = 0; k < 128; ++k) s += hp[k] * wp[k];
  out[mm * 8 + c] = s + bias[c];
}

extern "C" void kernel_launch(void* const* d_in, const int* in_sizes, int n_in,
                              void* d_out, int out_size, void* d_ws, size_t ws_size,
                              hipStream_t stream) {
  (void)in_sizes; (void)n_in; (void)out_size; (void)ws_size;
  const float* x    = (const float*)d_in[0];
  const float* Wih0 = (const float*)d_in[1];
  const float* Whh0 = (const float*)d_in[2];
  const float* bih0 = (const float*)d_in[3];
  const float* bhh0 = (const float*)d_in[4];
  const float* Wih1 = (const float*)d_in[5];
  const float* Whh1 = (const float*)d_in[6];
  const float* bih1 = (const float*)d_in[7];
  const float* bhh1 = (const float*)d_in[8];
  const float* gatW = (const float*)d_in[9];
  const float* gatA = (const float*)d_in[10];
  const float* lng  = (const float*)d_in[11];
  const float* lnb  = (const float*)d_in[12];
  const float* inw  = (const float*)d_in[13];
  const float* inb  = (const float*)d_in[14];
  const float* outw = (const float*)d_in[15];
  const float* outb = (const float*)d_in[16];
  const float* f1w  = (const float*)d_in[17];
  const float* f1b  = (const float*)d_in[18];
  const float* f2w  = (const float*)d_in[19];
  const float* f2b  = (const float*)d_in[20];
  float* out = (float*)d_out;
  float* ws = (float*)d_ws;

  // fp32 regions:
  float* XPA   = ws;                  // 16384*768: xp0 -> xp1 -> qkv
  float* G0    = ws + 12582912;       // gat_out (gru0 fp32 h never stored)
  float* G1    = G0 + 4194304;        // gru1-out (fp32, for ln_res)
  float* Yb    = G1 + 4194304;        // [f16 G0_16 | f16 G1_16] -> attn_out fp32
  float* HGAT  = Yb + 4194304;        // gat feats fp32 -> [f16 CTX16 | f16 Y16]
  float* GATWTf= HGAT + 4194304;
  float* FSRC  = GATWTf + 65536;
  float* FDST  = FSRC + 65536;
  float* POOL  = FDST + 65536;
  float* HIDb  = POOL + 8192;
  float* W16b  = HIDb + 4096;         // f16 weight pool (~1.1 MB)

  // f16 aliases (lifetimes verified against launch order):
  half_t* X16     = (half_t*)G1;                   // dead before gru1 writes G1
  half_t* G0_16   = (half_t*)Yb;                   // dead before attn_out write
  half_t* G1_16   = (half_t*)(Yb + 2097152);
  half_t* CTX16   = (half_t*)HGAT;                 // written after gat phase done
  half_t* Y16     = (half_t*)(HGAT + 2097152);
  half_t* GATWT16 = (half_t*)GATWTf;
  half_t* W16ih0  = (half_t*)W16b;
  half_t* W16ih1  = (half_t*)(W16b + 49152);
  half_t* W16in   = (half_t*)(W16b + 49152 + 98304);
  half_t* W16out  = (half_t*)(W16b + 49152 + 98304 + 98304);

  // 0. casts (weights once; x once)
  castk<<<2048, 256, 0, stream>>>(x, X16, 2097152);
  castk<<<96, 256, 0, stream>>>(Wih0, W16ih0, 98304);
  castk<<<192, 256, 0, stream>>>(Wih1, W16ih1, 196608);
  castk<<<192, 256, 0, stream>>>(inw, W16in, 196608);
  castk<<<64, 256, 0, stream>>>(outw, W16out, 65536);
  gat_wt<<<256, 256, 0, stream>>>(gatW, GATWT16);
  // 1. xp0 = x @ W_ih0^T + b_ih0   (MFMA f16)
  gemm_f16<<<dim3(12, 128), 256, 0, stream>>>(X16, W16ih0, bih0, XPA, 16384, 768, 128);
  // 2. GRU layer 0 (fp32 h not needed -> nullptr)
  gru_layer<<<32, 512, 0, stream>>>(XPA, Whh0, bhh0, nullptr, G0_16);
  // 3. xp1 = g0 @ W_ih1^T + b_ih1
  gemm_f16<<<dim3(12, 128), 256, 0, stream>>>(G0_16, W16ih1, bih1, XPA, 16384, 768, 256);
  // 4. GRU layer 1
  gru_layer<<<32, 512, 0, stream>>>(XPA, Whh1, bhh1, G1, G1_16);
  // 5. GAT per-head features + attention
  gemm_f16<<<dim3(4, 128), 256, 0, stream>>>(G1_16, GATWT16, nullptr, HGAT, 16384, 256, 256);
  gat_fsd<<<dim3(32, 4), 512, 0, stream>>>(HGAT, gatA, FSRC, FDST);
  gat_attn<<<dim3(16, 4, 32), 256, 0, stream>>>(HGAT, FSRC, FDST, G0);
  // 6. y = LN(g + gat_out) -> f16
  ln_res<<<4096, 256, 0, stream>>>(G1, G0, lng, lnb, Y16);
  // 7. MHA
  gemm_f16<<<dim3(12, 128), 256, 0, stream>>>(Y16, W16in, inb, XPA, 16384, 768, 256);
  mha_attn<<<dim3(16, 4, 32), 256, 0, stream>>>(XPA, CTX16);
  gemm_f16<<<dim3(4, 128), 256, 0, stream>>>(CTX16, W16out, outb, Yb, 16384, 256, 256);
  // 8. pool + FC head
  mean_pool<<<32, 256, 0, stream>>>(Yb, POOL);
  fc1_k<<<32, 128, 0, stream>>>(POOL, f1w, f1b, HIDb);
  fc2_k<<<1, 256, 0, stream>>>(HIDb, f2w, f2b, out);
}